// Round 1
// baseline (1178.674 us; speedup 1.0000x reference)
//
#include <hip/hip_runtime.h>

#define N_NODES 50000
#define N_EDGES 800000
#define N_GRAPHS 64

__global__ void k_deg_init(float* deg, int n) {
    int i = blockIdx.x * blockDim.x + threadIdx.x;
    if (i < n) deg[i] = 1.0f;  // self-loop contributes 1
}

__global__ void k_deg_count(const int* dst, float* deg, int E) {
    int e = blockIdx.x * blockDim.x + threadIdx.x;
    if (e < E) atomicAdd(&deg[dst[e]], 1.0f);
}

__global__ void k_rsqrt_inplace(float* deg, int n) {
    int i = blockIdx.x * blockDim.x + threadIdx.x;
    if (i < n) deg[i] = rsqrtf(deg[i]);
}

// h0[N,64] = x[N,6] @ W_in[6,64] + b_in
__global__ void k_proj(const float* __restrict__ x, const float* __restrict__ W,
                       const float* __restrict__ b, float* __restrict__ h0, int n) {
    int t = blockIdx.x * blockDim.x + threadIdx.x;
    if (t >= n * 64) return;
    int i = t >> 6, j = t & 63;
    float acc = b[j];
#pragma unroll
    for (int k = 0; k < 6; k++) acc += x[i * 6 + k] * W[k * 64 + j];
    h0[t] = acc;
}

// out[N,128] = h[N,K] @ W[K,128]   (bias applied later, post-aggregation)
template <int K>
__global__ void k_lin(const float* __restrict__ h, const float* __restrict__ W,
                      float* __restrict__ out, int n) {
    int t = blockIdx.x * blockDim.x + threadIdx.x;
    if (t >= n * 128) return;
    int i = t >> 7, j = t & 127;
    const float* hr = h + (size_t)i * K;
    float acc = 0.f;
#pragma unroll
    for (int k = 0; k < K; k++) acc += hr[k] * W[k * 128 + j];
    out[t] = acc;
}

// self-loop term: out[i] = hw[i] * dinv[i]^2
__global__ void k_agg_init(const float* __restrict__ hw, const float* __restrict__ dinv,
                           float* __restrict__ out, int n) {
    int t = blockIdx.x * blockDim.x + threadIdx.x;
    if (t >= n * 128) return;
    int i = t >> 7;
    float di = dinv[i];
    out[t] = hw[t] * di * di;
}

// scatter: out[dst] += hw[src] * dinv[src]*dinv[dst]
__global__ void k_agg_edges(const int* __restrict__ src, const int* __restrict__ dst,
                            const float* __restrict__ hw, const float* __restrict__ dinv,
                            float* __restrict__ out, int E) {
    int t = blockIdx.x * blockDim.x + threadIdx.x;
    if (t >= E * 128) return;
    int e = t >> 7, j = t & 127;
    int s = src[e], d = dst[e];
    float nrm = dinv[s] * dinv[d];
    atomicAdd(&out[(size_t)d * 128 + j], hw[(size_t)s * 128 + j] * nrm);
}

__global__ void k_bias_relu(float* __restrict__ h, const float* __restrict__ b, int n) {
    int t = blockIdx.x * blockDim.x + threadIdx.x;
    if (t >= n * 128) return;
    float v = h[t] + b[t & 127];
    h[t] = v > 0.f ? v : 0.f;
}

__global__ void k_pool_init(float* psum, float* pmax, float* pcnt) {
    int t = blockIdx.x * blockDim.x + threadIdx.x;
    if (t < N_GRAPHS * 128) { psum[t] = 0.f; pmax[t] = 0.f; }
    if (t < N_GRAPHS) pcnt[t] = 0.f;
}

// batch is sorted: accumulate locally over a chunk of nodes, flush atomics
// only when the graph id changes (~1-2 flushes per 64-node chunk).
__global__ void k_pool(const float* __restrict__ h, const int* __restrict__ batch,
                       float* psum, float* pmax, float* pcnt, int n) {
    const int CH = 64;
    int t = blockIdx.x * blockDim.x + threadIdx.x;
    int c = t & 127;
    int chunk = t >> 7;
    int i0 = chunk * CH;
    if (i0 >= n) return;
    int i1 = min(i0 + CH, n);
    float s = 0.f, m = 0.f;
    int cnt = 0;
    int g = batch[i0];
    for (int i = i0; i < i1; i++) {
        int gi = batch[i];
        if (gi != g) {
            atomicAdd(&psum[g * 128 + c], s);
            atomicMax((int*)&pmax[g * 128 + c], __float_as_int(m));
            if (c == 0) atomicAdd(&pcnt[g], (float)cnt);
            s = 0.f; m = 0.f; cnt = 0; g = gi;
        }
        float v = h[(size_t)i * 128 + c];  // post-relu, >= 0
        s += v;
        m = fmaxf(m, v);
        cnt++;
    }
    atomicAdd(&psum[g * 128 + c], s);
    atomicMax((int*)&pmax[g * 128 + c], __float_as_int(m));
    if (c == 0) atomicAdd(&pcnt[g], (float)cnt);
}

// out[G,256] = relu(concat(mean, max) @ Wp[256,256] + bp)
__global__ void k_final(const float* __restrict__ psum, const float* __restrict__ pmax,
                        const float* __restrict__ pcnt, const float* __restrict__ Wp,
                        const float* __restrict__ bp, float* __restrict__ out) {
    int t = blockIdx.x * blockDim.x + threadIdx.x;
    if (t >= N_GRAPHS * 256) return;
    int g = t >> 8, j = t & 255;
    float inv = 1.0f / fmaxf(pcnt[g], 1.0f);
    float acc = bp[j];
#pragma unroll 4
    for (int k = 0; k < 128; k++) acc += (psum[g * 128 + k] * inv) * Wp[k * 256 + j];
#pragma unroll 4
    for (int k = 0; k < 128; k++) acc += pmax[g * 128 + k] * Wp[(128 + k) * 256 + j];
    out[t] = fmaxf(acc, 0.f);
}

extern "C" void kernel_launch(void* const* d_in, const int* in_sizes, int n_in,
                              void* d_out, int out_size, void* d_ws, size_t ws_size,
                              hipStream_t stream) {
    const int N = N_NODES, E = N_EDGES;
    const float* x    = (const float*)d_in[0];
    const int*   ei   = (const int*)d_in[1];
    const int*   src  = ei;
    const int*   dst  = ei + E;
    const int*   batch= (const int*)d_in[2];
    const float* W_in = (const float*)d_in[3];
    const float* b_in = (const float*)d_in[4];
    const float* W1   = (const float*)d_in[5];
    const float* b1   = (const float*)d_in[6];
    const float* W2   = (const float*)d_in[7];
    const float* b2   = (const float*)d_in[8];
    const float* Wp   = (const float*)d_in[9];
    const float* bp   = (const float*)d_in[10];
    float* out = (float*)d_out;

    float* ws = (float*)d_ws;
    float* dinv = ws;                      // N (padded to 50048)
    float* A    = ws + 50048;              // N*128
    float* B    = A + (size_t)N_NODES * 128;  // N*128
    float* psum = B + (size_t)N_NODES * 128;  // 64*128
    float* pmax = psum + N_GRAPHS * 128;      // 64*128
    float* pcnt = pmax + N_GRAPHS * 128;      // 64

    const int TB = 256;
    dim3 blk(TB);
    int gN    = (N + TB - 1) / TB;
    int gE    = (E + TB - 1) / TB;
    int gN64  = (N * 64 + TB - 1) / TB;
    int gN128 = (N * 128 + TB - 1) / TB;
    int gE128 = (int)(((long long)E * 128 + TB - 1) / TB);

    // degree + dinv
    k_deg_init<<<gN, blk, 0, stream>>>(dinv, N);
    k_deg_count<<<gE, blk, 0, stream>>>(dst, dinv, E);
    k_rsqrt_inplace<<<gN, blk, 0, stream>>>(dinv, N);

    // input projection: A[0:N*64] = h0
    k_proj<<<gN64, blk, 0, stream>>>(x, W_in, b_in, A, N);

    // layer 1: B = h0 @ W1 ; A = agg(B) ; relu(A + b1)
    k_lin<64><<<gN128, blk, 0, stream>>>(A, W1, B, N);
    k_agg_init<<<gN128, blk, 0, stream>>>(B, dinv, A, N);
    k_agg_edges<<<gE128, blk, 0, stream>>>(src, dst, B, dinv, A, E);
    k_bias_relu<<<gN128, blk, 0, stream>>>(A, b1, N);

    // layer 2: B = h1 @ W2 ; A = agg(B) ; relu(A + b2)
    k_lin<128><<<gN128, blk, 0, stream>>>(A, W2, B, N);
    k_agg_init<<<gN128, blk, 0, stream>>>(B, dinv, A, N);
    k_agg_edges<<<gE128, blk, 0, stream>>>(src, dst, B, dinv, A, E);
    k_bias_relu<<<gN128, blk, 0, stream>>>(A, b2, N);

    // pooling
    k_pool_init<<<(N_GRAPHS * 128 + TB - 1) / TB, blk, 0, stream>>>(psum, pmax, pcnt);
    int chunks = (N + 63) / 64;
    k_pool<<<(chunks * 128 + TB - 1) / TB, blk, 0, stream>>>(A, batch, psum, pmax, pcnt, N);

    // final MLP
    k_final<<<(N_GRAPHS * 256 + TB - 1) / TB, blk, 0, stream>>>(psum, pmax, pcnt, Wp, bp, out);
}

// Round 2
// 755.846 us; speedup vs baseline: 1.5594x; 1.5594x over previous
//
#include <hip/hip_runtime.h>

#define N_NODES 50000
#define N_EDGES 800000
#define N_GRAPHS 64

// ---------------- CSR build ----------------

__global__ void k_zero_int(int* p, int n) {
    int i = blockIdx.x * blockDim.x + threadIdx.x;
    if (i < n) p[i] = 0;
}

__global__ void k_deg_count(const int* __restrict__ dst, int* __restrict__ deg, int E) {
    int e = blockIdx.x * blockDim.x + threadIdx.x;
    if (e < E) atomicAdd(&deg[dst[e]], 1);
}

// one block of 256 threads: exclusive scan of deg -> row_ptr, cursor
__global__ void k_scan_rowptr(const int* __restrict__ deg, int* __restrict__ row_ptr,
                              int* __restrict__ cursor, int n) {
    __shared__ int part[256];
    int t = threadIdx.x;
    int per = (n + 255) >> 8;
    int i0 = t * per, i1 = min(i0 + per, n);
    int s = 0;
    for (int i = i0; i < i1; i++) s += deg[i];
    part[t] = s;
    __syncthreads();
    // Hillis-Steele inclusive scan
    for (int off = 1; off < 256; off <<= 1) {
        int u = (t >= off) ? part[t - off] : 0;
        __syncthreads();
        part[t] += u;
        __syncthreads();
    }
    int off = part[t] - s;  // exclusive prefix
    for (int i = i0; i < i1; i++) {
        row_ptr[i] = off;
        cursor[i] = off;
        off += deg[i];
    }
    if (t == 255) row_ptr[n] = off;
}

__global__ void k_fill_csr(const int* __restrict__ src, const int* __restrict__ dst,
                           int* __restrict__ cursor, int* __restrict__ col, int E) {
    int e = blockIdx.x * blockDim.x + threadIdx.x;
    if (e < E) {
        int d = dst[e];
        int slot = atomicAdd(&cursor[d], 1);
        col[slot] = src[e];
    }
}

__global__ void k_dinv(const int* __restrict__ deg, float* __restrict__ dinv, int n) {
    int i = blockIdx.x * blockDim.x + threadIdx.x;
    if (i < n) dinv[i] = rsqrtf((float)(deg[i] + 1));  // +1 self-loop
}

// ---------------- dense / fused ----------------

// g0[i,j] = dinv[i] * (x[i]·W_in[:,j] + b_in[j])   (N x 64)
__global__ void k_proj_scale(const float* __restrict__ x, const float* __restrict__ W,
                             const float* __restrict__ b, const float* __restrict__ dinv,
                             float* __restrict__ g0, int n) {
    int t = blockIdx.x * blockDim.x + threadIdx.x;
    if (t >= n * 64) return;
    int i = t >> 6, j = t & 63;
    float acc = b[j];
#pragma unroll
    for (int k = 0; k < 6; k++) acc += x[i * 6 + k] * W[k * 64 + j];
    g0[t] = acc * dinv[i];
}

// gather: s[i] = g[i] + sum_{e: dst=i} g[col[e]]    (C channels/row)
template <int C>
__global__ void k_gather(const float* __restrict__ g, const int* __restrict__ row_ptr,
                         const int* __restrict__ col, float* __restrict__ s_out, int n) {
    int t = blockIdx.x * blockDim.x + threadIdx.x;
    if (t >= n * C) return;
    int i = t / C;
    int c = t & (C - 1);
    float acc = g[(size_t)i * C + c];
    float acc2 = 0.f;
    int e = row_ptr[i], e1 = row_ptr[i + 1];
    for (; e + 1 < e1; e += 2) {
        int s0 = col[e], s1 = col[e + 1];
        acc  += g[(size_t)s0 * C + c];
        acc2 += g[(size_t)s1 * C + c];
    }
    if (e < e1) acc += g[(size_t)col[e] * C + c];
    s_out[t] = acc + acc2;
}

// h[i,j] = relu(dinv[i]*(s[i]·W[:,j]) + b[j]); store (WRITE_G ? dinv[i]*h : h)
template <int K, bool WRITE_G>
__global__ void k_lin_fused(const float* __restrict__ s, const float* __restrict__ W,
                            const float* __restrict__ b, const float* __restrict__ dinv,
                            float* __restrict__ out, int n) {
    int t = blockIdx.x * blockDim.x + threadIdx.x;
    if (t >= n * 128) return;
    int i = t >> 7, j = t & 127;
    const float* sr = s + (size_t)i * K;
    float acc = 0.f;
#pragma unroll
    for (int k = 0; k < K; k++) acc += sr[k] * W[k * 128 + j];
    float di = dinv[i];
    float v = fmaxf(di * acc + b[j], 0.f);
    out[t] = WRITE_G ? di * v : v;
}

// ---------------- pooling + final ----------------

__global__ void k_pool_init(float* psum, float* pmax, float* pcnt) {
    int t = blockIdx.x * blockDim.x + threadIdx.x;
    if (t < N_GRAPHS * 128) { psum[t] = 0.f; pmax[t] = 0.f; }
    if (t < N_GRAPHS) pcnt[t] = 0.f;
}

// batch sorted: chunked accumulate, flush on segment change
__global__ void k_pool(const float* __restrict__ h, const int* __restrict__ batch,
                       float* psum, float* pmax, float* pcnt, int n) {
    const int CH = 64;
    int t = blockIdx.x * blockDim.x + threadIdx.x;
    int c = t & 127;
    int chunk = t >> 7;
    int i0 = chunk * CH;
    if (i0 >= n) return;
    int i1 = min(i0 + CH, n);
    float s = 0.f, m = 0.f;
    int cnt = 0;
    int g = batch[i0];
    for (int i = i0; i < i1; i++) {
        int gi = batch[i];
        if (gi != g) {
            atomicAdd(&psum[g * 128 + c], s);
            atomicMax((int*)&pmax[g * 128 + c], __float_as_int(m));
            if (c == 0) atomicAdd(&pcnt[g], (float)cnt);
            s = 0.f; m = 0.f; cnt = 0; g = gi;
        }
        float v = h[(size_t)i * 128 + c];  // post-relu, >= 0
        s += v;
        m = fmaxf(m, v);
        cnt++;
    }
    atomicAdd(&psum[g * 128 + c], s);
    atomicMax((int*)&pmax[g * 128 + c], __float_as_int(m));
    if (c == 0) atomicAdd(&pcnt[g], (float)cnt);
}

__global__ void k_final(const float* __restrict__ psum, const float* __restrict__ pmax,
                        const float* __restrict__ pcnt, const float* __restrict__ Wp,
                        const float* __restrict__ bp, float* __restrict__ out) {
    int t = blockIdx.x * blockDim.x + threadIdx.x;
    if (t >= N_GRAPHS * 256) return;
    int g = t >> 8, j = t & 255;
    float inv = 1.0f / fmaxf(pcnt[g], 1.0f);
    float acc = bp[j];
#pragma unroll 4
    for (int k = 0; k < 128; k++) acc += (psum[g * 128 + k] * inv) * Wp[k * 256 + j];
#pragma unroll 4
    for (int k = 0; k < 128; k++) acc += pmax[g * 128 + k] * Wp[(128 + k) * 256 + j];
    out[t] = fmaxf(acc, 0.f);
}

extern "C" void kernel_launch(void* const* d_in, const int* in_sizes, int n_in,
                              void* d_out, int out_size, void* d_ws, size_t ws_size,
                              hipStream_t stream) {
    const int N = N_NODES, E = N_EDGES;
    const float* x    = (const float*)d_in[0];
    const int*   ei   = (const int*)d_in[1];
    const int*   src  = ei;
    const int*   dst  = ei + E;
    const int*   batch= (const int*)d_in[2];
    const float* W_in = (const float*)d_in[3];
    const float* b_in = (const float*)d_in[4];
    const float* W1   = (const float*)d_in[5];
    const float* b1   = (const float*)d_in[6];
    const float* W2   = (const float*)d_in[7];
    const float* b2   = (const float*)d_in[8];
    const float* Wp   = (const float*)d_in[9];
    const float* bp   = (const float*)d_in[10];
    float* out = (float*)d_out;

    char* p = (char*)d_ws;
    int* deg     = (int*)p;      p += 50048 * 4;
    int* row_ptr = (int*)p;      p += 50048 * 4;
    int* cursor  = (int*)p;      p += 50048 * 4;
    int* col     = (int*)p;      p += (size_t)N_EDGES * 4;
    float* dinv  = (float*)p;    p += 50048 * 4;
    float* A     = (float*)p;    p += (size_t)N_NODES * 128 * 4;
    float* B     = (float*)p;    p += (size_t)N_NODES * 128 * 4;
    float* psum  = (float*)p;    p += N_GRAPHS * 128 * 4;
    float* pmax  = (float*)p;    p += N_GRAPHS * 128 * 4;
    float* pcnt  = (float*)p;

    const int TB = 256;
    dim3 blk(TB);
    int gN    = (N + TB - 1) / TB;
    int gE    = (E + TB - 1) / TB;
    int gN64  = (N * 64 + TB - 1) / TB;
    int gN128 = (N * 128 + TB - 1) / TB;

    // CSR build + dinv
    k_zero_int<<<gN, blk, 0, stream>>>(deg, N);
    k_deg_count<<<gE, blk, 0, stream>>>(dst, deg, E);
    k_scan_rowptr<<<1, blk, 0, stream>>>(deg, row_ptr, cursor, N);
    k_fill_csr<<<gE, blk, 0, stream>>>(src, dst, cursor, col, E);
    k_dinv<<<gN, blk, 0, stream>>>(deg, dinv, N);

    // g0 = dinv * (x@W_in + b_in)   [N,64] in A
    k_proj_scale<<<gN64, blk, 0, stream>>>(x, W_in, b_in, dinv, A, N);

    // layer 1: s0 = gather(g0) in B ; g1 = dinv*relu(dinv*s0@W1 + b1) in A
    k_gather<64><<<gN64, blk, 0, stream>>>(A, row_ptr, col, B, N);
    k_lin_fused<64, true><<<gN128, blk, 0, stream>>>(B, W1, b1, dinv, A, N);

    // layer 2: s1 = gather(g1) in B ; h2 = relu(dinv*s1@W2 + b2) in A
    k_gather<128><<<gN128, blk, 0, stream>>>(A, row_ptr, col, B, N);
    k_lin_fused<128, false><<<gN128, blk, 0, stream>>>(B, W2, b2, dinv, A, N);

    // pooling
    k_pool_init<<<(N_GRAPHS * 128 + TB - 1) / TB, blk, 0, stream>>>(psum, pmax, pcnt);
    int chunks = (N + 63) / 64;
    k_pool<<<(chunks * 128 + TB - 1) / TB, blk, 0, stream>>>(A, batch, psum, pmax, pcnt, N);

    // final MLP
    k_final<<<(N_GRAPHS * 256 + TB - 1) / TB, blk, 0, stream>>>(psum, pmax, pcnt, Wp, bp, out);
}

// Round 3
// 494.612 us; speedup vs baseline: 2.3830x; 1.5282x over previous
//
#include <hip/hip_runtime.h>

#define N_NODES 50000
#define N_EDGES 800000
#define N_GRAPHS 64
#define N_PAD 50048

// ---------------- CSR build ----------------

__global__ void k_zero_int(int* p, int n) {
    int i = blockIdx.x * blockDim.x + threadIdx.x;
    if (i < n) p[i] = 0;
}

__global__ void k_deg_count(const int* __restrict__ dst, int* __restrict__ deg, int E) {
    int e = blockIdx.x * blockDim.x + threadIdx.x;
    if (e < E) atomicAdd(&deg[dst[e]], 1);
}

// one block of 256 threads: exclusive scan of deg -> row_ptr, cursor
__global__ void k_scan_rowptr(const int* __restrict__ deg, int* __restrict__ row_ptr,
                              int* __restrict__ cursor, int n) {
    __shared__ int part[256];
    int t = threadIdx.x;
    int per = (n + 255) >> 8;
    int i0 = t * per, i1 = min(i0 + per, n);
    int s = 0;
    for (int i = i0; i < i1; i++) s += deg[i];
    part[t] = s;
    __syncthreads();
    for (int off = 1; off < 256; off <<= 1) {
        int u = (t >= off) ? part[t - off] : 0;
        __syncthreads();
        part[t] += u;
        __syncthreads();
    }
    int off = part[t] - s;  // exclusive prefix
    for (int i = i0; i < i1; i++) {
        row_ptr[i] = off;
        cursor[i] = off;
        off += deg[i];
    }
    if (t == 255) row_ptr[n] = off;
}

__global__ void k_fill_csr(const int* __restrict__ src, const int* __restrict__ dst,
                           int* __restrict__ cursor, int* __restrict__ col, int E) {
    int e = blockIdx.x * blockDim.x + threadIdx.x;
    if (e < E) {
        int d = dst[e];
        int slot = atomicAdd(&cursor[d], 1);
        col[slot] = src[e];
    }
}

__global__ void k_dinv(const int* __restrict__ deg, float* __restrict__ dinv, int n) {
    int i = blockIdx.x * blockDim.x + threadIdx.x;
    if (i < n) dinv[i] = rsqrtf((float)(deg[i] + 1));  // +1 self-loop
}

// ---------------- dense ----------------

// g0[i,j] = dinv[i] * (x[i]·W_in[:,j] + b_in[j])   (N x 64), float4 over j
__global__ void k_proj_scale(const float* __restrict__ x, const float* __restrict__ W,
                             const float* __restrict__ b, const float* __restrict__ dinv,
                             float* __restrict__ g0, int n) {
    int t = blockIdx.x * blockDim.x + threadIdx.x;
    if (t >= n * 16) return;
    int i = t >> 4, jq = t & 15;
    float4 acc = *(const float4*)&b[jq * 4];
#pragma unroll
    for (int k = 0; k < 6; k++) {
        float xv = x[i * 6 + k];
        float4 w = *(const float4*)&W[k * 64 + jq * 4];
        acc.x += xv * w.x; acc.y += xv * w.y; acc.z += xv * w.z; acc.w += xv * w.w;
    }
    float di = dinv[i];
    acc.x *= di; acc.y *= di; acc.z *= di; acc.w *= di;
    *(float4*)&g0[(size_t)i * 64 + jq * 4] = acc;
}

// gather: s[i] = g[i] + sum_{e: dst=i} g[col[e]]   (C floats/row, float4 per thread)
template <int C>
__global__ void k_gather(const float* __restrict__ g, const int* __restrict__ row_ptr,
                         const int* __restrict__ col, float* __restrict__ s_out, int n) {
    constexpr int CQ = C / 4;
    int t = blockIdx.x * blockDim.x + threadIdx.x;
    if (t >= n * CQ) return;
    int i = t / CQ;
    int c = t & (CQ - 1);
    const float4* g4 = (const float4*)g;
    float4 acc = g4[(size_t)i * CQ + c];
    float4 acc2 = {0.f, 0.f, 0.f, 0.f};
    int e = row_ptr[i], e1 = row_ptr[i + 1];
    for (; e + 1 < e1; e += 2) {
        float4 v0 = g4[(size_t)col[e] * CQ + c];
        float4 v1 = g4[(size_t)col[e + 1] * CQ + c];
        acc.x += v0.x; acc.y += v0.y; acc.z += v0.z; acc.w += v0.w;
        acc2.x += v1.x; acc2.y += v1.y; acc2.z += v1.z; acc2.w += v1.w;
    }
    if (e < e1) {
        float4 v = g4[(size_t)col[e] * CQ + c];
        acc.x += v.x; acc.y += v.y; acc.z += v.z; acc.w += v.w;
    }
    acc.x += acc2.x; acc.y += acc2.y; acc.z += acc2.z; acc.w += acc2.w;
    ((float4*)s_out)[t] = acc;
}

// Tiled GEMM: out[N,128] = epilogue(s[N,K] @ W[K,128])
// block: 32 rows x 128 cols, 256 threads, thread = 4 rows x 4 cols
// epilogue: v = relu(dinv[i]*acc + b[j]); store WRITE_G ? dinv[i]*v : v
template <int K, bool WRITE_G>
__global__ __launch_bounds__(256) void k_lin_tiled(
        const float* __restrict__ s, const float* __restrict__ W,
        const float* __restrict__ b, const float* __restrict__ dinv,
        float* __restrict__ out, int n) {
    __shared__ float Wlds[K * 128];
    int t = threadIdx.x;
    for (int idx = t * 4; idx < K * 128; idx += 256 * 4)
        *(float4*)&Wlds[idx] = *(const float4*)&W[idx];
    __syncthreads();

    int cq = t & 31;   // col quad: cols cq*4 .. cq*4+3
    int rg = t >> 5;   // row group 0..7
    int row0 = blockIdx.x * 32 + rg * 4;
    int r0 = min(row0 + 0, n - 1);
    int r1 = min(row0 + 1, n - 1);
    int r2 = min(row0 + 2, n - 1);
    int r3 = min(row0 + 3, n - 1);
    const float* sr0 = s + (size_t)r0 * K;
    const float* sr1 = s + (size_t)r1 * K;
    const float* sr2 = s + (size_t)r2 * K;
    const float* sr3 = s + (size_t)r3 * K;

    float4 acc[4] = {};
    for (int k = 0; k < K; k += 4) {
        float4 a0 = *(const float4*)&sr0[k];
        float4 a1 = *(const float4*)&sr1[k];
        float4 a2 = *(const float4*)&sr2[k];
        float4 a3 = *(const float4*)&sr3[k];
#pragma unroll
        for (int kk = 0; kk < 4; kk++) {
            float4 w = *(float4*)&Wlds[(k + kk) * 128 + cq * 4];
            float av0 = kk == 0 ? a0.x : kk == 1 ? a0.y : kk == 2 ? a0.z : a0.w;
            float av1 = kk == 0 ? a1.x : kk == 1 ? a1.y : kk == 2 ? a1.z : a1.w;
            float av2 = kk == 0 ? a2.x : kk == 1 ? a2.y : kk == 2 ? a2.z : a2.w;
            float av3 = kk == 0 ? a3.x : kk == 1 ? a3.y : kk == 2 ? a3.z : a3.w;
            acc[0].x += av0 * w.x; acc[0].y += av0 * w.y; acc[0].z += av0 * w.z; acc[0].w += av0 * w.w;
            acc[1].x += av1 * w.x; acc[1].y += av1 * w.y; acc[1].z += av1 * w.z; acc[1].w += av1 * w.w;
            acc[2].x += av2 * w.x; acc[2].y += av2 * w.y; acc[2].z += av2 * w.z; acc[2].w += av2 * w.w;
            acc[3].x += av3 * w.x; acc[3].y += av3 * w.y; acc[3].z += av3 * w.z; acc[3].w += av3 * w.w;
        }
    }

    float4 bb = *(const float4*)&b[cq * 4];
#pragma unroll
    for (int r = 0; r < 4; r++) {
        int row = row0 + r;
        if (row < n) {
            float di = dinv[row];
            float4 v;
            v.x = fmaxf(di * acc[r].x + bb.x, 0.f);
            v.y = fmaxf(di * acc[r].y + bb.y, 0.f);
            v.z = fmaxf(di * acc[r].z + bb.z, 0.f);
            v.w = fmaxf(di * acc[r].w + bb.w, 0.f);
            if (WRITE_G) { v.x *= di; v.y *= di; v.z *= di; v.w *= di; }
            *(float4*)&out[(size_t)row * 128 + cq * 4] = v;
        }
    }
}

// ---------------- pooling + final ----------------

__global__ void k_pool_init(float* psum, float* pmax, float* pcnt) {
    int t = blockIdx.x * blockDim.x + threadIdx.x;
    if (t < N_GRAPHS * 128) { psum[t] = 0.f; pmax[t] = 0.f; }
    if (t < N_GRAPHS) pcnt[t] = 0.f;
}

// batch sorted: chunked accumulate (float4 over channels), flush on segment change
__global__ void k_pool(const float* __restrict__ h, const int* __restrict__ batch,
                       float* psum, float* pmax, float* pcnt, int n) {
    const int CH = 64;
    int t = blockIdx.x * blockDim.x + threadIdx.x;
    int c = t & 31;       // channel quad
    int chunk = t >> 5;
    int i0 = chunk * CH;
    if (i0 >= n) return;
    int i1 = min(i0 + CH, n);
    const float4* h4 = (const float4*)h;
    float4 s = {0, 0, 0, 0}, m = {0, 0, 0, 0};
    int cnt = 0;
    int g = batch[i0];
    for (int i = i0; i < i1; i++) {
        int gi = batch[i];
        if (gi != g) {
            atomicAdd(&psum[g * 128 + c * 4 + 0], s.x);
            atomicAdd(&psum[g * 128 + c * 4 + 1], s.y);
            atomicAdd(&psum[g * 128 + c * 4 + 2], s.z);
            atomicAdd(&psum[g * 128 + c * 4 + 3], s.w);
            atomicMax((int*)&pmax[g * 128 + c * 4 + 0], __float_as_int(m.x));
            atomicMax((int*)&pmax[g * 128 + c * 4 + 1], __float_as_int(m.y));
            atomicMax((int*)&pmax[g * 128 + c * 4 + 2], __float_as_int(m.z));
            atomicMax((int*)&pmax[g * 128 + c * 4 + 3], __float_as_int(m.w));
            if (c == 0) atomicAdd(&pcnt[g], (float)cnt);
            s = {0, 0, 0, 0}; m = {0, 0, 0, 0}; cnt = 0; g = gi;
        }
        float4 v = h4[(size_t)i * 32 + c];  // post-relu, >= 0
        s.x += v.x; s.y += v.y; s.z += v.z; s.w += v.w;
        m.x = fmaxf(m.x, v.x); m.y = fmaxf(m.y, v.y);
        m.z = fmaxf(m.z, v.z); m.w = fmaxf(m.w, v.w);
        cnt++;
    }
    atomicAdd(&psum[g * 128 + c * 4 + 0], s.x);
    atomicAdd(&psum[g * 128 + c * 4 + 1], s.y);
    atomicAdd(&psum[g * 128 + c * 4 + 2], s.z);
    atomicAdd(&psum[g * 128 + c * 4 + 3], s.w);
    atomicMax((int*)&pmax[g * 128 + c * 4 + 0], __float_as_int(m.x));
    atomicMax((int*)&pmax[g * 128 + c * 4 + 1], __float_as_int(m.y));
    atomicMax((int*)&pmax[g * 128 + c * 4 + 2], __float_as_int(m.z));
    atomicMax((int*)&pmax[g * 128 + c * 4 + 3], __float_as_int(m.w));
    if (c == 0) atomicAdd(&pcnt[g], (float)cnt);
}

__global__ void k_final(const float* __restrict__ psum, const float* __restrict__ pmax,
                        const float* __restrict__ pcnt, const float* __restrict__ Wp,
                        const float* __restrict__ bp, float* __restrict__ out) {
    int t = blockIdx.x * blockDim.x + threadIdx.x;
    if (t >= N_GRAPHS * 256) return;
    int g = t >> 8, j = t & 255;
    float inv = 1.0f / fmaxf(pcnt[g], 1.0f);
    float acc = bp[j];
#pragma unroll 4
    for (int k = 0; k < 128; k++) acc += (psum[g * 128 + k] * inv) * Wp[k * 256 + j];
#pragma unroll 4
    for (int k = 0; k < 128; k++) acc += pmax[g * 128 + k] * Wp[(128 + k) * 256 + j];
    out[t] = fmaxf(acc, 0.f);
}

extern "C" void kernel_launch(void* const* d_in, const int* in_sizes, int n_in,
                              void* d_out, int out_size, void* d_ws, size_t ws_size,
                              hipStream_t stream) {
    const int N = N_NODES, E = N_EDGES;
    const float* x    = (const float*)d_in[0];
    const int*   ei   = (const int*)d_in[1];
    const int*   src  = ei;
    const int*   dst  = ei + E;
    const int*   batch= (const int*)d_in[2];
    const float* W_in = (const float*)d_in[3];
    const float* b_in = (const float*)d_in[4];
    const float* W1   = (const float*)d_in[5];
    const float* b1   = (const float*)d_in[6];
    const float* W2   = (const float*)d_in[7];
    const float* b2   = (const float*)d_in[8];
    const float* Wp   = (const float*)d_in[9];
    const float* bp   = (const float*)d_in[10];
    float* out = (float*)d_out;

    char* p = (char*)d_ws;
    int* deg     = (int*)p;      p += N_PAD * 4;
    int* row_ptr = (int*)p;      p += N_PAD * 4;
    int* cursor  = (int*)p;      p += N_PAD * 4;
    int* col     = (int*)p;      p += (size_t)N_EDGES * 4;
    float* dinv  = (float*)p;    p += N_PAD * 4;
    float* A     = (float*)p;    p += (size_t)N_PAD * 128 * 4;
    float* B     = (float*)p;    p += (size_t)N_PAD * 128 * 4;
    float* psum  = (float*)p;    p += N_GRAPHS * 128 * 4;
    float* pmax  = (float*)p;    p += N_GRAPHS * 128 * 4;
    float* pcnt  = (float*)p;

    const int TB = 256;
    dim3 blk(TB);
    int gN   = (N + TB - 1) / TB;
    int gE   = (E + TB - 1) / TB;
    int gN16 = (N * 16 + TB - 1) / TB;
    int gN32 = (N * 32 + TB - 1) / TB;
    int gGemm = (N + 31) / 32;

    // CSR build + dinv
    k_zero_int<<<gN, blk, 0, stream>>>(deg, N);
    k_deg_count<<<gE, blk, 0, stream>>>(dst, deg, E);
    k_scan_rowptr<<<1, blk, 0, stream>>>(deg, row_ptr, cursor, N);
    k_fill_csr<<<gE, blk, 0, stream>>>(src, dst, cursor, col, E);
    k_dinv<<<gN, blk, 0, stream>>>(deg, dinv, N);

    // g0 = dinv * (x@W_in + b_in)   [N,64] in A
    k_proj_scale<<<gN16, blk, 0, stream>>>(x, W_in, b_in, dinv, A, N);

    // layer 1: s0 = gather(g0) in B ; g1 = dinv*relu(dinv*(s0@W1) + b1) in A
    k_gather<64><<<gN16, blk, 0, stream>>>(A, row_ptr, col, B, N);
    k_lin_tiled<64, true><<<gGemm, blk, 0, stream>>>(B, W1, b1, dinv, A, N);

    // layer 2: s1 = gather(g1) in B ; h2 = relu(dinv*(s1@W2) + b2) in A
    k_gather<128><<<gN32, blk, 0, stream>>>(A, row_ptr, col, B, N);
    k_lin_tiled<128, false><<<gGemm, blk, 0, stream>>>(B, W2, b2, dinv, A, N);

    // pooling
    k_pool_init<<<(N_GRAPHS * 128 + TB - 1) / TB, blk, 0, stream>>>(psum, pmax, pcnt);
    int chunks = (N + 63) / 64;
    k_pool<<<(chunks * 32 + TB - 1) / TB, blk, 0, stream>>>(A, batch, psum, pmax, pcnt, N);

    // final MLP
    k_final<<<(N_GRAPHS * 256 + TB - 1) / TB, blk, 0, stream>>>(psum, pmax, pcnt, Wp, bp, out);
}

// Round 4
// 383.445 us; speedup vs baseline: 3.0739x; 1.2899x over previous
//
#include <hip/hip_runtime.h>

#define N_NODES 50000
#define N_EDGES 800000
#define N_GRAPHS 64
#define N_PAD 50048
#define SCAN_NB ((N_NODES + 255) / 256)   // 196 blocks

// ---------------- CSR build ----------------

__global__ void k_zero_int(int* p, int n) {
    int i = blockIdx.x * blockDim.x + threadIdx.x;
    if (i < n) p[i] = 0;
}

__global__ void k_deg_count(const int* __restrict__ dst, int* __restrict__ deg, int E) {
    int e = blockIdx.x * blockDim.x + threadIdx.x;
    if (e < E) atomicAdd(&deg[dst[e]], 1);
}

// phase 1: per-block sum of 256 deg values
__global__ void k_block_sum(const int* __restrict__ deg, int* __restrict__ bsum, int n) {
    __shared__ int sh[256];
    int t = threadIdx.x;
    int i = blockIdx.x * 256 + t;
    sh[t] = (i < n) ? deg[i] : 0;
    __syncthreads();
    for (int off = 128; off > 0; off >>= 1) {
        if (t < off) sh[t] += sh[t + off];
        __syncthreads();
    }
    if (t == 0) bsum[blockIdx.x] = sh[0];
}

// phase 2: one block, exclusive scan of nb block sums (nb <= 256)
__global__ void k_bsum_scan(const int* __restrict__ bsum, int* __restrict__ bscan, int nb) {
    __shared__ int sh[256];
    int t = threadIdx.x;
    int v = (t < nb) ? bsum[t] : 0;
    sh[t] = v;
    __syncthreads();
    for (int off = 1; off < 256; off <<= 1) {
        int u = (t >= off) ? sh[t - off] : 0;
        __syncthreads();
        sh[t] += u;
        __syncthreads();
    }
    if (t < nb) bscan[t] = sh[t] - v;  // exclusive
}

// phase 3: per-block inclusive scan + offset -> row_ptr, cursor
__global__ void k_write_rowptr(const int* __restrict__ deg, const int* __restrict__ bscan,
                               int* __restrict__ row_ptr, int* __restrict__ cursor, int n) {
    __shared__ int sh[256];
    int t = threadIdx.x;
    int i = blockIdx.x * 256 + t;
    int v = (i < n) ? deg[i] : 0;
    sh[t] = v;
    __syncthreads();
    for (int off = 1; off < 256; off <<= 1) {
        int u = (t >= off) ? sh[t - off] : 0;
        __syncthreads();
        sh[t] += u;
        __syncthreads();
    }
    int excl = sh[t] - v + bscan[blockIdx.x];
    if (i < n) {
        row_ptr[i] = excl;
        cursor[i] = excl;
        if (i == n - 1) row_ptr[n] = excl + v;
    }
}

__global__ void k_fill_csr(const int* __restrict__ src, const int* __restrict__ dst,
                           int* __restrict__ cursor, int* __restrict__ col, int E) {
    int e = blockIdx.x * blockDim.x + threadIdx.x;
    if (e < E) {
        int d = dst[e];
        int slot = atomicAdd(&cursor[d], 1);
        col[slot] = src[e];
    }
}

__global__ void k_dinv(const int* __restrict__ deg, float* __restrict__ dinv, int n) {
    int i = blockIdx.x * blockDim.x + threadIdx.x;
    if (i < n) dinv[i] = rsqrtf((float)(deg[i] + 1));  // +1 self-loop
}

// ---------------- dense ----------------

// g0[i,j] = dinv[i] * (x[i]·W_in[:,j] + b_in[j])   (N x 64), float4 over j
__global__ void k_proj_scale(const float* __restrict__ x, const float* __restrict__ W,
                             const float* __restrict__ b, const float* __restrict__ dinv,
                             float* __restrict__ g0, int n) {
    int t = blockIdx.x * blockDim.x + threadIdx.x;
    if (t >= n * 16) return;
    int i = t >> 4, jq = t & 15;
    float4 acc = *(const float4*)&b[jq * 4];
#pragma unroll
    for (int k = 0; k < 6; k++) {
        float xv = x[i * 6 + k];
        float4 w = *(const float4*)&W[k * 64 + jq * 4];
        acc.x += xv * w.x; acc.y += xv * w.y; acc.z += xv * w.z; acc.w += xv * w.w;
    }
    float di = dinv[i];
    acc.x *= di; acc.y *= di; acc.z *= di; acc.w *= di;
    *(float4*)&g0[(size_t)i * 64 + jq * 4] = acc;
}

// gather: s[i] = g[i] + sum_{e: dst=i} g[col[e]]   (C floats/row, float4 per thread)
template <int C>
__global__ void k_gather(const float* __restrict__ g, const int* __restrict__ row_ptr,
                         const int* __restrict__ col, float* __restrict__ s_out, int n) {
    constexpr int CQ = C / 4;
    int t = blockIdx.x * blockDim.x + threadIdx.x;
    if (t >= n * CQ) return;
    int i = t / CQ;
    int c = t & (CQ - 1);
    const float4* g4 = (const float4*)g;
    float4 acc = g4[(size_t)i * CQ + c];
    float4 acc2 = {0.f, 0.f, 0.f, 0.f};
    int e = row_ptr[i], e1 = row_ptr[i + 1];
    for (; e + 1 < e1; e += 2) {
        float4 v0 = g4[(size_t)col[e] * CQ + c];
        float4 v1 = g4[(size_t)col[e + 1] * CQ + c];
        acc.x += v0.x; acc.y += v0.y; acc.z += v0.z; acc.w += v0.w;
        acc2.x += v1.x; acc2.y += v1.y; acc2.z += v1.z; acc2.w += v1.w;
    }
    if (e < e1) {
        float4 v = g4[(size_t)col[e] * CQ + c];
        acc.x += v.x; acc.y += v.y; acc.z += v.z; acc.w += v.w;
    }
    acc.x += acc2.x; acc.y += acc2.y; acc.z += acc2.z; acc.w += acc2.w;
    ((float4*)s_out)[t] = acc;
}

// Tiled GEMM: out[N,128] = epilogue(s[N,K] @ W[K,128])
// block: 32 rows x 128 cols, 256 threads, thread = 4 rows x 4 cols
template <int K, bool WRITE_G>
__global__ __launch_bounds__(256) void k_lin_tiled(
        const float* __restrict__ s, const float* __restrict__ W,
        const float* __restrict__ b, const float* __restrict__ dinv,
        float* __restrict__ out, int n) {
    __shared__ float Wlds[K * 128];
    int t = threadIdx.x;
    for (int idx = t * 4; idx < K * 128; idx += 256 * 4)
        *(float4*)&Wlds[idx] = *(const float4*)&W[idx];
    __syncthreads();

    int cq = t & 31;
    int rg = t >> 5;
    int row0 = blockIdx.x * 32 + rg * 4;
    int r0 = min(row0 + 0, n - 1);
    int r1 = min(row0 + 1, n - 1);
    int r2 = min(row0 + 2, n - 1);
    int r3 = min(row0 + 3, n - 1);
    const float* sr0 = s + (size_t)r0 * K;
    const float* sr1 = s + (size_t)r1 * K;
    const float* sr2 = s + (size_t)r2 * K;
    const float* sr3 = s + (size_t)r3 * K;

    float4 acc[4] = {};
    for (int k = 0; k < K; k += 4) {
        float4 a0 = *(const float4*)&sr0[k];
        float4 a1 = *(const float4*)&sr1[k];
        float4 a2 = *(const float4*)&sr2[k];
        float4 a3 = *(const float4*)&sr3[k];
#pragma unroll
        for (int kk = 0; kk < 4; kk++) {
            float4 w = *(float4*)&Wlds[(k + kk) * 128 + cq * 4];
            float av0 = kk == 0 ? a0.x : kk == 1 ? a0.y : kk == 2 ? a0.z : a0.w;
            float av1 = kk == 0 ? a1.x : kk == 1 ? a1.y : kk == 2 ? a1.z : a1.w;
            float av2 = kk == 0 ? a2.x : kk == 1 ? a2.y : kk == 2 ? a2.z : a2.w;
            float av3 = kk == 0 ? a3.x : kk == 1 ? a3.y : kk == 2 ? a3.z : a3.w;
            acc[0].x += av0 * w.x; acc[0].y += av0 * w.y; acc[0].z += av0 * w.z; acc[0].w += av0 * w.w;
            acc[1].x += av1 * w.x; acc[1].y += av1 * w.y; acc[1].z += av1 * w.z; acc[1].w += av1 * w.w;
            acc[2].x += av2 * w.x; acc[2].y += av2 * w.y; acc[2].z += av2 * w.z; acc[2].w += av2 * w.w;
            acc[3].x += av3 * w.x; acc[3].y += av3 * w.y; acc[3].z += av3 * w.z; acc[3].w += av3 * w.w;
        }
    }

    float4 bb = *(const float4*)&b[cq * 4];
#pragma unroll
    for (int r = 0; r < 4; r++) {
        int row = row0 + r;
        if (row < n) {
            float di = dinv[row];
            float4 v;
            v.x = fmaxf(di * acc[r].x + bb.x, 0.f);
            v.y = fmaxf(di * acc[r].y + bb.y, 0.f);
            v.z = fmaxf(di * acc[r].z + bb.z, 0.f);
            v.w = fmaxf(di * acc[r].w + bb.w, 0.f);
            if (WRITE_G) { v.x *= di; v.y *= di; v.z *= di; v.w *= di; }
            *(float4*)&out[(size_t)row * 128 + cq * 4] = v;
        }
    }
}

// ---------------- pooling + final ----------------

__global__ void k_pool_init(float* psum, float* pmax, float* pcnt) {
    int t = blockIdx.x * blockDim.x + threadIdx.x;
    if (t < N_GRAPHS * 128) { psum[t] = 0.f; pmax[t] = 0.f; }
    if (t < N_GRAPHS) pcnt[t] = 0.f;
}

// batch sorted: chunked accumulate (float4 over channels), flush on segment change
__global__ void k_pool(const float* __restrict__ h, const int* __restrict__ batch,
                       float* psum, float* pmax, float* pcnt, int n) {
    const int CH = 64;
    int t = blockIdx.x * blockDim.x + threadIdx.x;
    int c = t & 31;
    int chunk = t >> 5;
    int i0 = chunk * CH;
    if (i0 >= n) return;
    int i1 = min(i0 + CH, n);
    const float4* h4 = (const float4*)h;
    float4 s = {0, 0, 0, 0}, m = {0, 0, 0, 0};
    int cnt = 0;
    int g = batch[i0];
    for (int i = i0; i < i1; i++) {
        int gi = batch[i];
        if (gi != g) {
            atomicAdd(&psum[g * 128 + c * 4 + 0], s.x);
            atomicAdd(&psum[g * 128 + c * 4 + 1], s.y);
            atomicAdd(&psum[g * 128 + c * 4 + 2], s.z);
            atomicAdd(&psum[g * 128 + c * 4 + 3], s.w);
            atomicMax((int*)&pmax[g * 128 + c * 4 + 0], __float_as_int(m.x));
            atomicMax((int*)&pmax[g * 128 + c * 4 + 1], __float_as_int(m.y));
            atomicMax((int*)&pmax[g * 128 + c * 4 + 2], __float_as_int(m.z));
            atomicMax((int*)&pmax[g * 128 + c * 4 + 3], __float_as_int(m.w));
            if (c == 0) atomicAdd(&pcnt[g], (float)cnt);
            s = {0, 0, 0, 0}; m = {0, 0, 0, 0}; cnt = 0; g = gi;
        }
        float4 v = h4[(size_t)i * 32 + c];
        s.x += v.x; s.y += v.y; s.z += v.z; s.w += v.w;
        m.x = fmaxf(m.x, v.x); m.y = fmaxf(m.y, v.y);
        m.z = fmaxf(m.z, v.z); m.w = fmaxf(m.w, v.w);
        cnt++;
    }
    atomicAdd(&psum[g * 128 + c * 4 + 0], s.x);
    atomicAdd(&psum[g * 128 + c * 4 + 1], s.y);
    atomicAdd(&psum[g * 128 + c * 4 + 2], s.z);
    atomicAdd(&psum[g * 128 + c * 4 + 3], s.w);
    atomicMax((int*)&pmax[g * 128 + c * 4 + 0], __float_as_int(m.x));
    atomicMax((int*)&pmax[g * 128 + c * 4 + 1], __float_as_int(m.y));
    atomicMax((int*)&pmax[g * 128 + c * 4 + 2], __float_as_int(m.z));
    atomicMax((int*)&pmax[g * 128 + c * 4 + 3], __float_as_int(m.w));
    if (c == 0) atomicAdd(&pcnt[g], (float)cnt);
}

__global__ void k_final(const float* __restrict__ psum, const float* __restrict__ pmax,
                        const float* __restrict__ pcnt, const float* __restrict__ Wp,
                        const float* __restrict__ bp, float* __restrict__ out) {
    int t = blockIdx.x * blockDim.x + threadIdx.x;
    if (t >= N_GRAPHS * 256) return;
    int g = t >> 8, j = t & 255;
    float inv = 1.0f / fmaxf(pcnt[g], 1.0f);
    float acc = bp[j];
#pragma unroll 4
    for (int k = 0; k < 128; k++) acc += (psum[g * 128 + k] * inv) * Wp[k * 256 + j];
#pragma unroll 4
    for (int k = 0; k < 128; k++) acc += pmax[g * 128 + k] * Wp[(128 + k) * 256 + j];
    out[t] = fmaxf(acc, 0.f);
}

extern "C" void kernel_launch(void* const* d_in, const int* in_sizes, int n_in,
                              void* d_out, int out_size, void* d_ws, size_t ws_size,
                              hipStream_t stream) {
    const int N = N_NODES, E = N_EDGES;
    const float* x    = (const float*)d_in[0];
    const int*   ei   = (const int*)d_in[1];
    const int*   src  = ei;
    const int*   dst  = ei + E;
    const int*   batch= (const int*)d_in[2];
    const float* W_in = (const float*)d_in[3];
    const float* b_in = (const float*)d_in[4];
    const float* W1   = (const float*)d_in[5];
    const float* b1   = (const float*)d_in[6];
    const float* W2   = (const float*)d_in[7];
    const float* b2   = (const float*)d_in[8];
    const float* Wp   = (const float*)d_in[9];
    const float* bp   = (const float*)d_in[10];
    float* out = (float*)d_out;

    char* p = (char*)d_ws;
    int* deg     = (int*)p;      p += N_PAD * 4;
    int* row_ptr = (int*)p;      p += N_PAD * 4;
    int* cursor  = (int*)p;      p += N_PAD * 4;
    int* bsum    = (int*)p;      p += 256 * 4;
    int* bscan   = (int*)p;      p += 256 * 4;
    int* col     = (int*)p;      p += (size_t)N_EDGES * 4;
    float* dinv  = (float*)p;    p += N_PAD * 4;
    float* A     = (float*)p;    p += (size_t)N_PAD * 128 * 4;
    float* B     = (float*)p;    p += (size_t)N_PAD * 128 * 4;
    float* psum  = (float*)p;    p += N_GRAPHS * 128 * 4;
    float* pmax  = (float*)p;    p += N_GRAPHS * 128 * 4;
    float* pcnt  = (float*)p;

    const int TB = 256;
    dim3 blk(TB);
    int gN   = (N + TB - 1) / TB;
    int gE   = (E + TB - 1) / TB;
    int gN16 = (N * 16 + TB - 1) / TB;
    int gN32 = (N * 32 + TB - 1) / TB;
    int gGemm = (N + 31) / 32;

    // CSR build + dinv (grid-parallel 3-phase scan)
    k_zero_int<<<gN, blk, 0, stream>>>(deg, N);
    k_deg_count<<<gE, blk, 0, stream>>>(dst, deg, E);
    k_block_sum<<<SCAN_NB, blk, 0, stream>>>(deg, bsum, N);
    k_bsum_scan<<<1, blk, 0, stream>>>(bsum, bscan, SCAN_NB);
    k_write_rowptr<<<SCAN_NB, blk, 0, stream>>>(deg, bscan, row_ptr, cursor, N);
    k_fill_csr<<<gE, blk, 0, stream>>>(src, dst, cursor, col, E);
    k_dinv<<<gN, blk, 0, stream>>>(deg, dinv, N);

    // g0 = dinv * (x@W_in + b_in)   [N,64] in A
    k_proj_scale<<<gN16, blk, 0, stream>>>(x, W_in, b_in, dinv, A, N);

    // layer 1: s0 = gather(g0) in B ; g1 = dinv*relu(dinv*(s0@W1) + b1) in A
    k_gather<64><<<gN16, blk, 0, stream>>>(A, row_ptr, col, B, N);
    k_lin_tiled<64, true><<<gGemm, blk, 0, stream>>>(B, W1, b1, dinv, A, N);

    // layer 2: s1 = gather(g1) in B ; h2 = relu(dinv*(s1@W2) + b2) in A
    k_gather<128><<<gN32, blk, 0, stream>>>(A, row_ptr, col, B, N);
    k_lin_tiled<128, false><<<gGemm, blk, 0, stream>>>(B, W2, b2, dinv, A, N);

    // pooling
    k_pool_init<<<(N_GRAPHS * 128 + TB - 1) / TB, blk, 0, stream>>>(psum, pmax, pcnt);
    int chunks = (N + 63) / 64;
    k_pool<<<(chunks * 32 + TB - 1) / TB, blk, 0, stream>>>(A, batch, psum, pmax, pcnt, N);

    // final MLP
    k_final<<<(N_GRAPHS * 256 + TB - 1) / TB, blk, 0, stream>>>(psum, pmax, pcnt, Wp, bp, out);
}

// Round 5
// 352.886 us; speedup vs baseline: 3.3401x; 1.0866x over previous
//
#include <hip/hip_runtime.h>
#include <hip/hip_fp16.h>

#define N_NODES 50000
#define N_EDGES 800000
#define N_GRAPHS 64
#define N_PAD 50048
#define SCAN_NB ((N_NODES + 255) / 256)   // 196 blocks

// ---------------- CSR build ----------------

__global__ void k_zero_int(int* p, int n) {
    int i = blockIdx.x * blockDim.x + threadIdx.x;
    if (i < n) p[i] = 0;
}

__global__ void k_deg_count(const int* __restrict__ dst, int* __restrict__ deg, int E) {
    int e = blockIdx.x * blockDim.x + threadIdx.x;
    if (e < E) atomicAdd(&deg[dst[e]], 1);
}

__global__ void k_block_sum(const int* __restrict__ deg, int* __restrict__ bsum, int n) {
    __shared__ int sh[256];
    int t = threadIdx.x;
    int i = blockIdx.x * 256 + t;
    sh[t] = (i < n) ? deg[i] : 0;
    __syncthreads();
    for (int off = 128; off > 0; off >>= 1) {
        if (t < off) sh[t] += sh[t + off];
        __syncthreads();
    }
    if (t == 0) bsum[blockIdx.x] = sh[0];
}

__global__ void k_bsum_scan(const int* __restrict__ bsum, int* __restrict__ bscan, int nb) {
    __shared__ int sh[256];
    int t = threadIdx.x;
    int v = (t < nb) ? bsum[t] : 0;
    sh[t] = v;
    __syncthreads();
    for (int off = 1; off < 256; off <<= 1) {
        int u = (t >= off) ? sh[t - off] : 0;
        __syncthreads();
        sh[t] += u;
        __syncthreads();
    }
    if (t < nb) bscan[t] = sh[t] - v;  // exclusive
}

__global__ void k_write_rowptr(const int* __restrict__ deg, const int* __restrict__ bscan,
                               int* __restrict__ row_ptr, int* __restrict__ cursor, int n) {
    __shared__ int sh[256];
    int t = threadIdx.x;
    int i = blockIdx.x * 256 + t;
    int v = (i < n) ? deg[i] : 0;
    sh[t] = v;
    __syncthreads();
    for (int off = 1; off < 256; off <<= 1) {
        int u = (t >= off) ? sh[t - off] : 0;
        __syncthreads();
        sh[t] += u;
        __syncthreads();
    }
    int excl = sh[t] - v + bscan[blockIdx.x];
    if (i < n) {
        row_ptr[i] = excl;
        cursor[i] = excl;
        if (i == n - 1) row_ptr[n] = excl + v;
    }
}

__global__ void k_fill_csr(const int* __restrict__ src, const int* __restrict__ dst,
                           int* __restrict__ cursor, int* __restrict__ col, int E) {
    int e = blockIdx.x * blockDim.x + threadIdx.x;
    if (e < E) {
        int d = dst[e];
        int slot = atomicAdd(&cursor[d], 1);
        col[slot] = src[e];
    }
}

__global__ void k_dinv(const int* __restrict__ deg, float* __restrict__ dinv, int n) {
    int i = blockIdx.x * blockDim.x + threadIdx.x;
    if (i < n) dinv[i] = rsqrtf((float)(deg[i] + 1));  // +1 self-loop
}

// ---------------- dense ----------------

// g0[i,j] = fp16( dinv[i] * (x[i]·W_in[:,j] + b_in[j]) )   (N x 64)
__global__ void k_proj_scale(const float* __restrict__ x, const float* __restrict__ W,
                             const float* __restrict__ b, const float* __restrict__ dinv,
                             __half* __restrict__ g0, int n) {
    int t = blockIdx.x * blockDim.x + threadIdx.x;
    if (t >= n * 16) return;
    int i = t >> 4, jq = t & 15;
    float4 acc = *(const float4*)&b[jq * 4];
#pragma unroll
    for (int k = 0; k < 6; k++) {
        float xv = x[i * 6 + k];
        float4 w = *(const float4*)&W[k * 64 + jq * 4];
        acc.x += xv * w.x; acc.y += xv * w.y; acc.z += xv * w.z; acc.w += xv * w.w;
    }
    float di = dinv[i];
    union { __half2 h[2]; uint2 u; } pk;
    pk.h[0] = __floats2half2_rn(acc.x * di, acc.y * di);
    pk.h[1] = __floats2half2_rn(acc.z * di, acc.w * di);
    *(uint2*)&g0[(size_t)i * 64 + jq * 4] = pk.u;
}

// fp16 gather: s[i] = g[i] + sum_{e: dst=i} g[col[e]]; fp32 accumulate.
// 8 channels per thread, one 16B load (8 halves) per edge.
struct H8 { __half2 a, b, c, d; };

template <int C>
__global__ void k_gather_h(const H8* __restrict__ g, const int* __restrict__ row_ptr,
                           const int* __restrict__ col, float* __restrict__ s_out, int n) {
    constexpr int CO = C / 8;  // H8-chunks per row
    int t = blockIdx.x * blockDim.x + threadIdx.x;
    if (t >= n * CO) return;
    int i = t / CO;
    int c = t & (CO - 1);
    float acc[8] = {};
    auto addv = [&](H8 v) {
        float2 f;
        f = __half22float2(v.a); acc[0] += f.x; acc[1] += f.y;
        f = __half22float2(v.b); acc[2] += f.x; acc[3] += f.y;
        f = __half22float2(v.c); acc[4] += f.x; acc[5] += f.y;
        f = __half22float2(v.d); acc[6] += f.x; acc[7] += f.y;
    };
    addv(g[(size_t)i * CO + c]);  // self term
    int e = row_ptr[i], e1 = row_ptr[i + 1];
    for (; e + 1 < e1; e += 2) {
        H8 v0 = g[(size_t)col[e] * CO + c];
        H8 v1 = g[(size_t)col[e + 1] * CO + c];
        addv(v0);
        addv(v1);
    }
    if (e < e1) addv(g[(size_t)col[e] * CO + c]);
    float4* o = (float4*)&s_out[(size_t)i * C + c * 8];
    o[0] = make_float4(acc[0], acc[1], acc[2], acc[3]);
    o[1] = make_float4(acc[4], acc[5], acc[6], acc[7]);
}

// Tiled GEMM: out[N,128] = epilogue(s[N,K] @ W[K,128])
// block: 32 rows x 128 cols, 256 threads, thread = 4 rows x 4 cols
// HALF_OUT: v = relu(di*acc + b); store fp16(di*v)   (g for next gather)
// else:     store fp32 relu(di*acc + b)
template <int K, bool HALF_OUT>
__global__ __launch_bounds__(256) void k_lin_tiled(
        const float* __restrict__ s, const float* __restrict__ W,
        const float* __restrict__ b, const float* __restrict__ dinv,
        void* __restrict__ outp, int n) {
    __shared__ float Wlds[K * 128];
    int t = threadIdx.x;
    for (int idx = t * 4; idx < K * 128; idx += 256 * 4)
        *(float4*)&Wlds[idx] = *(const float4*)&W[idx];
    __syncthreads();

    int cq = t & 31;
    int rg = t >> 5;
    int row0 = blockIdx.x * 32 + rg * 4;
    int r0 = min(row0 + 0, n - 1);
    int r1 = min(row0 + 1, n - 1);
    int r2 = min(row0 + 2, n - 1);
    int r3 = min(row0 + 3, n - 1);
    const float* sr0 = s + (size_t)r0 * K;
    const float* sr1 = s + (size_t)r1 * K;
    const float* sr2 = s + (size_t)r2 * K;
    const float* sr3 = s + (size_t)r3 * K;

    float4 acc[4] = {};
    for (int k = 0; k < K; k += 4) {
        float4 a0 = *(const float4*)&sr0[k];
        float4 a1 = *(const float4*)&sr1[k];
        float4 a2 = *(const float4*)&sr2[k];
        float4 a3 = *(const float4*)&sr3[k];
#pragma unroll
        for (int kk = 0; kk < 4; kk++) {
            float4 w = *(float4*)&Wlds[(k + kk) * 128 + cq * 4];
            float av0 = kk == 0 ? a0.x : kk == 1 ? a0.y : kk == 2 ? a0.z : a0.w;
            float av1 = kk == 0 ? a1.x : kk == 1 ? a1.y : kk == 2 ? a1.z : a1.w;
            float av2 = kk == 0 ? a2.x : kk == 1 ? a2.y : kk == 2 ? a2.z : a2.w;
            float av3 = kk == 0 ? a3.x : kk == 1 ? a3.y : kk == 2 ? a3.z : a3.w;
            acc[0].x += av0 * w.x; acc[0].y += av0 * w.y; acc[0].z += av0 * w.z; acc[0].w += av0 * w.w;
            acc[1].x += av1 * w.x; acc[1].y += av1 * w.y; acc[1].z += av1 * w.z; acc[1].w += av1 * w.w;
            acc[2].x += av2 * w.x; acc[2].y += av2 * w.y; acc[2].z += av2 * w.z; acc[2].w += av2 * w.w;
            acc[3].x += av3 * w.x; acc[3].y += av3 * w.y; acc[3].z += av3 * w.z; acc[3].w += av3 * w.w;
        }
    }

    float4 bb = *(const float4*)&b[cq * 4];
#pragma unroll
    for (int r = 0; r < 4; r++) {
        int row = row0 + r;
        if (row < n) {
            float di = dinv[row];
            float4 v;
            v.x = fmaxf(di * acc[r].x + bb.x, 0.f);
            v.y = fmaxf(di * acc[r].y + bb.y, 0.f);
            v.z = fmaxf(di * acc[r].z + bb.z, 0.f);
            v.w = fmaxf(di * acc[r].w + bb.w, 0.f);
            if (HALF_OUT) {
                __half* out = (__half*)outp;
                union { __half2 h[2]; uint2 u; } pk;
                pk.h[0] = __floats2half2_rn(v.x * di, v.y * di);
                pk.h[1] = __floats2half2_rn(v.z * di, v.w * di);
                *(uint2*)&out[(size_t)row * 128 + cq * 4] = pk.u;
            } else {
                float* out = (float*)outp;
                *(float4*)&out[(size_t)row * 128 + cq * 4] = v;
            }
        }
    }
}

// ---------------- pooling + final ----------------

__global__ void k_pool_init(float* psum, float* pmax, float* pcnt) {
    int t = blockIdx.x * blockDim.x + threadIdx.x;
    if (t < N_GRAPHS * 128) { psum[t] = 0.f; pmax[t] = 0.f; }
    if (t < N_GRAPHS) pcnt[t] = 0.f;
}

__global__ void k_pool(const float* __restrict__ h, const int* __restrict__ batch,
                       float* psum, float* pmax, float* pcnt, int n) {
    const int CH = 64;
    int t = blockIdx.x * blockDim.x + threadIdx.x;
    int c = t & 31;
    int chunk = t >> 5;
    int i0 = chunk * CH;
    if (i0 >= n) return;
    int i1 = min(i0 + CH, n);
    const float4* h4 = (const float4*)h;
    float4 s = {0, 0, 0, 0}, m = {0, 0, 0, 0};
    int cnt = 0;
    int g = batch[i0];
    for (int i = i0; i < i1; i++) {
        int gi = batch[i];
        if (gi != g) {
            atomicAdd(&psum[g * 128 + c * 4 + 0], s.x);
            atomicAdd(&psum[g * 128 + c * 4 + 1], s.y);
            atomicAdd(&psum[g * 128 + c * 4 + 2], s.z);
            atomicAdd(&psum[g * 128 + c * 4 + 3], s.w);
            atomicMax((int*)&pmax[g * 128 + c * 4 + 0], __float_as_int(m.x));
            atomicMax((int*)&pmax[g * 128 + c * 4 + 1], __float_as_int(m.y));
            atomicMax((int*)&pmax[g * 128 + c * 4 + 2], __float_as_int(m.z));
            atomicMax((int*)&pmax[g * 128 + c * 4 + 3], __float_as_int(m.w));
            if (c == 0) atomicAdd(&pcnt[g], (float)cnt);
            s = {0, 0, 0, 0}; m = {0, 0, 0, 0}; cnt = 0; g = gi;
        }
        float4 v = h4[(size_t)i * 32 + c];
        s.x += v.x; s.y += v.y; s.z += v.z; s.w += v.w;
        m.x = fmaxf(m.x, v.x); m.y = fmaxf(m.y, v.y);
        m.z = fmaxf(m.z, v.z); m.w = fmaxf(m.w, v.w);
        cnt++;
    }
    atomicAdd(&psum[g * 128 + c * 4 + 0], s.x);
    atomicAdd(&psum[g * 128 + c * 4 + 1], s.y);
    atomicAdd(&psum[g * 128 + c * 4 + 2], s.z);
    atomicAdd(&psum[g * 128 + c * 4 + 3], s.w);
    atomicMax((int*)&pmax[g * 128 + c * 4 + 0], __float_as_int(m.x));
    atomicMax((int*)&pmax[g * 128 + c * 4 + 1], __float_as_int(m.y));
    atomicMax((int*)&pmax[g * 128 + c * 4 + 2], __float_as_int(m.z));
    atomicMax((int*)&pmax[g * 128 + c * 4 + 3], __float_as_int(m.w));
    if (c == 0) atomicAdd(&pcnt[g], (float)cnt);
}

__global__ void k_final(const float* __restrict__ psum, const float* __restrict__ pmax,
                        const float* __restrict__ pcnt, const float* __restrict__ Wp,
                        const float* __restrict__ bp, float* __restrict__ out) {
    int t = blockIdx.x * blockDim.x + threadIdx.x;
    if (t >= N_GRAPHS * 256) return;
    int g = t >> 8, j = t & 255;
    float inv = 1.0f / fmaxf(pcnt[g], 1.0f);
    float acc = bp[j];
#pragma unroll 4
    for (int k = 0; k < 128; k++) acc += (psum[g * 128 + k] * inv) * Wp[k * 256 + j];
#pragma unroll 4
    for (int k = 0; k < 128; k++) acc += pmax[g * 128 + k] * Wp[(128 + k) * 256 + j];
    out[t] = fmaxf(acc, 0.f);
}

extern "C" void kernel_launch(void* const* d_in, const int* in_sizes, int n_in,
                              void* d_out, int out_size, void* d_ws, size_t ws_size,
                              hipStream_t stream) {
    const int N = N_NODES, E = N_EDGES;
    const float* x    = (const float*)d_in[0];
    const int*   ei   = (const int*)d_in[1];
    const int*   src  = ei;
    const int*   dst  = ei + E;
    const int*   batch= (const int*)d_in[2];
    const float* W_in = (const float*)d_in[3];
    const float* b_in = (const float*)d_in[4];
    const float* W1   = (const float*)d_in[5];
    const float* b1   = (const float*)d_in[6];
    const float* W2   = (const float*)d_in[7];
    const float* b2   = (const float*)d_in[8];
    const float* Wp   = (const float*)d_in[9];
    const float* bp   = (const float*)d_in[10];
    float* out = (float*)d_out;

    char* p = (char*)d_ws;
    int* deg     = (int*)p;      p += N_PAD * 4;
    int* row_ptr = (int*)p;      p += N_PAD * 4;
    int* cursor  = (int*)p;      p += N_PAD * 4;
    int* bsum    = (int*)p;      p += 256 * 4;
    int* bscan   = (int*)p;      p += 256 * 4;
    int* col     = (int*)p;      p += (size_t)N_EDGES * 4;
    float* dinv  = (float*)p;    p += N_PAD * 4;
    float* A     = (float*)p;    p += (size_t)N_PAD * 128 * 4;  // holds fp16 g OR fp32 h2
    float* B     = (float*)p;    p += (size_t)N_PAD * 128 * 4;  // fp32 gather output s
    float* psum  = (float*)p;    p += N_GRAPHS * 128 * 4;
    float* pmax  = (float*)p;    p += N_GRAPHS * 128 * 4;
    float* pcnt  = (float*)p;
    __half* Ah = (__half*)A;

    const int TB = 256;
    dim3 blk(TB);
    int gN   = (N + TB - 1) / TB;
    int gE   = (E + TB - 1) / TB;
    int gN16 = (N * 16 + TB - 1) / TB;
    int gGemm = (N + 31) / 32;

    // CSR build + dinv (grid-parallel 3-phase scan)
    k_zero_int<<<gN, blk, 0, stream>>>(deg, N);
    k_deg_count<<<gE, blk, 0, stream>>>(dst, deg, E);
    k_block_sum<<<SCAN_NB, blk, 0, stream>>>(deg, bsum, N);
    k_bsum_scan<<<1, blk, 0, stream>>>(bsum, bscan, SCAN_NB);
    k_write_rowptr<<<SCAN_NB, blk, 0, stream>>>(deg, bscan, row_ptr, cursor, N);
    k_fill_csr<<<gE, blk, 0, stream>>>(src, dst, cursor, col, E);
    k_dinv<<<gN, blk, 0, stream>>>(deg, dinv, N);

    // g0 = fp16(dinv * (x@W_in + b_in))   [N,64] in Ah
    k_proj_scale<<<gN16, blk, 0, stream>>>(x, W_in, b_in, dinv, Ah, N);

    // layer 1: s0 = gather(g0) in B (fp32) ; g1 = fp16(dinv*relu(dinv*(s0@W1)+b1)) in Ah
    k_gather_h<64><<<(N * 8 + TB - 1) / TB, blk, 0, stream>>>((const H8*)Ah, row_ptr, col, B, N);
    k_lin_tiled<64, true><<<gGemm, blk, 0, stream>>>(B, W1, b1, dinv, Ah, N);

    // layer 2: s1 = gather(g1) in B ; h2 = relu(dinv*(s1@W2)+b2) fp32 in A
    k_gather_h<128><<<(N * 16 + TB - 1) / TB, blk, 0, stream>>>((const H8*)Ah, row_ptr, col, B, N);
    k_lin_tiled<128, false><<<gGemm, blk, 0, stream>>>(B, W2, b2, dinv, A, N);

    // pooling
    k_pool_init<<<(N_GRAPHS * 128 + TB - 1) / TB, blk, 0, stream>>>(psum, pmax, pcnt);
    int chunks = (N + 63) / 64;
    k_pool<<<(chunks * 32 + TB - 1) / TB, blk, 0, stream>>>(A, batch, psum, pmax, pcnt, N);

    // final MLP
    k_final<<<(N_GRAPHS * 256 + TB - 1) / TB, blk, 0, stream>>>(psum, pmax, pcnt, Wp, bp, out);
}

// Round 6
// 284.601 us; speedup vs baseline: 4.1415x; 1.2399x over previous
//
#include <hip/hip_runtime.h>
#include <hip/hip_fp16.h>

#define N_NODES 50000
#define N_EDGES 800000
#define N_GRAPHS 64
#define N_PAD 50048

#define CB 256                              // coarse-pass blocks
#define EPB (N_EDGES / CB)                  // 3125 edges per block (exact)
#define NBUCKET ((N_NODES + 255) / 256)     // 196 coarse buckets (dst>>8)
#define CMAT (NBUCKET * CB)                 // 50176 count-matrix entries
#define SCAN_NB ((CMAT + 255) / 256)        // 196 scan blocks

// ---------------- CSR build: two-level LDS counting sort ----------------

// per-block coarse histogram: counts[bucket * CB + blk]
__global__ __launch_bounds__(256) void k_coarse_hist(const int* __restrict__ dst,
                                                     int* __restrict__ counts) {
    __shared__ int hist[NBUCKET];
    int t = threadIdx.x, b = blockIdx.x;
    for (int i = t; i < NBUCKET; i += 256) hist[i] = 0;
    __syncthreads();
    int e0 = b * EPB;
    for (int e = e0 + t; e < e0 + EPB; e += 256)
        atomicAdd(&hist[dst[e] >> 8], 1);
    __syncthreads();
    for (int i = t; i < NBUCKET; i += 256)
        counts[i * CB + b] = hist[i];
}

// 3-phase grid scan over len ints
__global__ void k_block_sum(const int* __restrict__ v, int* __restrict__ bsum, int len) {
    __shared__ int sh[256];
    int t = threadIdx.x;
    int i = blockIdx.x * 256 + t;
    sh[t] = (i < len) ? v[i] : 0;
    __syncthreads();
    for (int off = 128; off > 0; off >>= 1) {
        if (t < off) sh[t] += sh[t + off];
        __syncthreads();
    }
    if (t == 0) bsum[blockIdx.x] = sh[0];
}

__global__ void k_bsum_scan(const int* __restrict__ bsum, int* __restrict__ bscan, int nb) {
    __shared__ int sh[256];
    int t = threadIdx.x;
    int v = (t < nb) ? bsum[t] : 0;
    sh[t] = v;
    __syncthreads();
    for (int off = 1; off < 256; off <<= 1) {
        int u = (t >= off) ? sh[t - off] : 0;
        __syncthreads();
        sh[t] += u;
        __syncthreads();
    }
    if (t < nb) bscan[t] = sh[t] - v;  // exclusive
}

__global__ void k_scan_write(const int* __restrict__ v, const int* __restrict__ bscan,
                             int* __restrict__ outx, int len) {
    __shared__ int sh[256];
    int t = threadIdx.x;
    int i = blockIdx.x * 256 + t;
    int x = (i < len) ? v[i] : 0;
    sh[t] = x;
    __syncthreads();
    for (int off = 1; off < 256; off <<= 1) {
        int u = (t >= off) ? sh[t - off] : 0;
        __syncthreads();
        sh[t] += u;
        __syncthreads();
    }
    if (i < len) outx[i] = sh[t] - x + bscan[blockIdx.x];
}

// scatter edges into coarse-sorted order; packed (dst<<32 | src), plain stores
__global__ __launch_bounds__(256) void k_coarse_scatter(
        const int* __restrict__ src, const int* __restrict__ dst,
        const int* __restrict__ cbase, unsigned long long* __restrict__ esort) {
    __shared__ int cur[NBUCKET];
    int t = threadIdx.x, b = blockIdx.x;
    for (int i = t; i < NBUCKET; i += 256) cur[i] = cbase[i * CB + b];
    __syncthreads();
    int e0 = b * EPB;
    for (int e = e0 + t; e < e0 + EPB; e += 256) {
        int d = dst[e];
        int slot = atomicAdd(&cur[d >> 8], 1);
        esort[slot] = ((unsigned long long)(unsigned)d << 32) | (unsigned)src[e];
    }
}

// one block per bucket: fine histogram -> deg/dinv/row_ptr, LDS-cursor fill of col
__global__ __launch_bounds__(256) void k_fine_fill(
        const unsigned long long* __restrict__ esort, const int* __restrict__ cbase,
        int* __restrict__ col, int* __restrict__ row_ptr, float* __restrict__ dinv) {
    __shared__ int hist[256];
    __shared__ int sc[256];
    __shared__ int cur[256];
    __shared__ int range[2];
    int t = threadIdx.x, b = blockIdx.x;
    hist[t] = 0;
    if (t == 0) {
        range[0] = cbase[b * CB];
        range[1] = (b + 1 < NBUCKET) ? cbase[(b + 1) * CB] : N_EDGES;
    }
    __syncthreads();
    int base = range[0], end = range[1];
    for (int e = base + t; e < end; e += 256)
        atomicAdd(&hist[(int)(esort[e] >> 32) & 255], 1);
    __syncthreads();
    int v = hist[t];
    sc[t] = v;
    __syncthreads();
    for (int off = 1; off < 256; off <<= 1) {
        int u = (t >= off) ? sc[t - off] : 0;
        __syncthreads();
        sc[t] += u;
        __syncthreads();
    }
    int start = base + sc[t] - v;  // exclusive within bucket + bucket base
    cur[t] = start;
    int node = b * 256 + t;
    if (node < N_NODES) {
        row_ptr[node] = start;
        dinv[node] = rsqrtf((float)(v + 1));  // +1 self-loop
    }
    if (b == 0 && t == 0) row_ptr[N_NODES] = N_EDGES;
    __syncthreads();
    for (int e = base + t; e < end; e += 256) {
        unsigned long long pk = esort[e];
        int slot = atomicAdd(&cur[(int)(pk >> 32) & 255], 1);
        col[slot] = (int)(pk & 0xffffffffu);
    }
}

// ---------------- dense ----------------

// g0[i,j] = fp16( dinv[i] * (x[i]·W_in[:,j] + b_in[j]) )   (N x 64)
__global__ void k_proj_scale(const float* __restrict__ x, const float* __restrict__ W,
                             const float* __restrict__ b, const float* __restrict__ dinv,
                             __half* __restrict__ g0, int n) {
    int t = blockIdx.x * blockDim.x + threadIdx.x;
    if (t >= n * 16) return;
    int i = t >> 4, jq = t & 15;
    float4 acc = *(const float4*)&b[jq * 4];
#pragma unroll
    for (int k = 0; k < 6; k++) {
        float xv = x[i * 6 + k];
        float4 w = *(const float4*)&W[k * 64 + jq * 4];
        acc.x += xv * w.x; acc.y += xv * w.y; acc.z += xv * w.z; acc.w += xv * w.w;
    }
    float di = dinv[i];
    union { __half2 h[2]; uint2 u; } pk;
    pk.h[0] = __floats2half2_rn(acc.x * di, acc.y * di);
    pk.h[1] = __floats2half2_rn(acc.z * di, acc.w * di);
    *(uint2*)&g0[(size_t)i * 64 + jq * 4] = pk.u;
}

// fp16 gather: s[i] = g[i] + sum_{e: dst=i} g[col[e]]; fp32 accumulate.
struct H8 { __half2 a, b, c, d; };

template <int C>
__global__ void k_gather_h(const H8* __restrict__ g, const int* __restrict__ row_ptr,
                           const int* __restrict__ col, float* __restrict__ s_out, int n) {
    constexpr int CO = C / 8;  // H8-chunks per row
    int t = blockIdx.x * blockDim.x + threadIdx.x;
    if (t >= n * CO) return;
    int i = t / CO;
    int c = t & (CO - 1);
    float acc[8] = {};
    auto addv = [&](H8 v) {
        float2 f;
        f = __half22float2(v.a); acc[0] += f.x; acc[1] += f.y;
        f = __half22float2(v.b); acc[2] += f.x; acc[3] += f.y;
        f = __half22float2(v.c); acc[4] += f.x; acc[5] += f.y;
        f = __half22float2(v.d); acc[6] += f.x; acc[7] += f.y;
    };
    addv(g[(size_t)i * CO + c]);  // self term
    int e = row_ptr[i], e1 = row_ptr[i + 1];
    for (; e + 1 < e1; e += 2) {
        H8 v0 = g[(size_t)col[e] * CO + c];
        H8 v1 = g[(size_t)col[e + 1] * CO + c];
        addv(v0);
        addv(v1);
    }
    if (e < e1) addv(g[(size_t)col[e] * CO + c]);
    float4* o = (float4*)&s_out[(size_t)i * C + c * 8];
    o[0] = make_float4(acc[0], acc[1], acc[2], acc[3]);
    o[1] = make_float4(acc[4], acc[5], acc[6], acc[7]);
}

// Tiled GEMM: out[N,128] = epilogue(s[N,K] @ W[K,128])
template <int K, bool HALF_OUT>
__global__ __launch_bounds__(256) void k_lin_tiled(
        const float* __restrict__ s, const float* __restrict__ W,
        const float* __restrict__ b, const float* __restrict__ dinv,
        void* __restrict__ outp, int n) {
    __shared__ float Wlds[K * 128];
    int t = threadIdx.x;
    for (int idx = t * 4; idx < K * 128; idx += 256 * 4)
        *(float4*)&Wlds[idx] = *(const float4*)&W[idx];
    __syncthreads();

    int cq = t & 31;
    int rg = t >> 5;
    int row0 = blockIdx.x * 32 + rg * 4;
    int r0 = min(row0 + 0, n - 1);
    int r1 = min(row0 + 1, n - 1);
    int r2 = min(row0 + 2, n - 1);
    int r3 = min(row0 + 3, n - 1);
    const float* sr0 = s + (size_t)r0 * K;
    const float* sr1 = s + (size_t)r1 * K;
    const float* sr2 = s + (size_t)r2 * K;
    const float* sr3 = s + (size_t)r3 * K;

    float4 acc[4] = {};
    for (int k = 0; k < K; k += 4) {
        float4 a0 = *(const float4*)&sr0[k];
        float4 a1 = *(const float4*)&sr1[k];
        float4 a2 = *(const float4*)&sr2[k];
        float4 a3 = *(const float4*)&sr3[k];
#pragma unroll
        for (int kk = 0; kk < 4; kk++) {
            float4 w = *(float4*)&Wlds[(k + kk) * 128 + cq * 4];
            float av0 = kk == 0 ? a0.x : kk == 1 ? a0.y : kk == 2 ? a0.z : a0.w;
            float av1 = kk == 0 ? a1.x : kk == 1 ? a1.y : kk == 2 ? a1.z : a1.w;
            float av2 = kk == 0 ? a2.x : kk == 1 ? a2.y : kk == 2 ? a2.z : a2.w;
            float av3 = kk == 0 ? a3.x : kk == 1 ? a3.y : kk == 2 ? a3.z : a3.w;
            acc[0].x += av0 * w.x; acc[0].y += av0 * w.y; acc[0].z += av0 * w.z; acc[0].w += av0 * w.w;
            acc[1].x += av1 * w.x; acc[1].y += av1 * w.y; acc[1].z += av1 * w.z; acc[1].w += av1 * w.w;
            acc[2].x += av2 * w.x; acc[2].y += av2 * w.y; acc[2].z += av2 * w.z; acc[2].w += av2 * w.w;
            acc[3].x += av3 * w.x; acc[3].y += av3 * w.y; acc[3].z += av3 * w.z; acc[3].w += av3 * w.w;
        }
    }

    float4 bb = *(const float4*)&b[cq * 4];
#pragma unroll
    for (int r = 0; r < 4; r++) {
        int row = row0 + r;
        if (row < n) {
            float di = dinv[row];
            float4 v;
            v.x = fmaxf(di * acc[r].x + bb.x, 0.f);
            v.y = fmaxf(di * acc[r].y + bb.y, 0.f);
            v.z = fmaxf(di * acc[r].z + bb.z, 0.f);
            v.w = fmaxf(di * acc[r].w + bb.w, 0.f);
            if (HALF_OUT) {
                __half* out = (__half*)outp;
                union { __half2 h[2]; uint2 u; } pk;
                pk.h[0] = __floats2half2_rn(v.x * di, v.y * di);
                pk.h[1] = __floats2half2_rn(v.z * di, v.w * di);
                *(uint2*)&out[(size_t)row * 128 + cq * 4] = pk.u;
            } else {
                float* out = (float*)outp;
                *(float4*)&out[(size_t)row * 128 + cq * 4] = v;
            }
        }
    }
}

// ---------------- pooling + final ----------------

__global__ void k_pool_init(float* psum, float* pmax, float* pcnt) {
    int t = blockIdx.x * blockDim.x + threadIdx.x;
    if (t < N_GRAPHS * 128) { psum[t] = 0.f; pmax[t] = 0.f; }
    if (t < N_GRAPHS) pcnt[t] = 0.f;
}

__global__ void k_pool(const float* __restrict__ h, const int* __restrict__ batch,
                       float* psum, float* pmax, float* pcnt, int n) {
    const int CH = 64;
    int t = blockIdx.x * blockDim.x + threadIdx.x;
    int c = t & 31;
    int chunk = t >> 5;
    int i0 = chunk * CH;
    if (i0 >= n) return;
    int i1 = min(i0 + CH, n);
    const float4* h4 = (const float4*)h;
    float4 s = {0, 0, 0, 0}, m = {0, 0, 0, 0};
    int cnt = 0;
    int g = batch[i0];
    for (int i = i0; i < i1; i++) {
        int gi = batch[i];
        if (gi != g) {
            atomicAdd(&psum[g * 128 + c * 4 + 0], s.x);
            atomicAdd(&psum[g * 128 + c * 4 + 1], s.y);
            atomicAdd(&psum[g * 128 + c * 4 + 2], s.z);
            atomicAdd(&psum[g * 128 + c * 4 + 3], s.w);
            atomicMax((int*)&pmax[g * 128 + c * 4 + 0], __float_as_int(m.x));
            atomicMax((int*)&pmax[g * 128 + c * 4 + 1], __float_as_int(m.y));
            atomicMax((int*)&pmax[g * 128 + c * 4 + 2], __float_as_int(m.z));
            atomicMax((int*)&pmax[g * 128 + c * 4 + 3], __float_as_int(m.w));
            if (c == 0) atomicAdd(&pcnt[g], (float)cnt);
            s = {0, 0, 0, 0}; m = {0, 0, 0, 0}; cnt = 0; g = gi;
        }
        float4 v = h4[(size_t)i * 32 + c];
        s.x += v.x; s.y += v.y; s.z += v.z; s.w += v.w;
        m.x = fmaxf(m.x, v.x); m.y = fmaxf(m.y, v.y);
        m.z = fmaxf(m.z, v.z); m.w = fmaxf(m.w, v.w);
        cnt++;
    }
    atomicAdd(&psum[g * 128 + c * 4 + 0], s.x);
    atomicAdd(&psum[g * 128 + c * 4 + 1], s.y);
    atomicAdd(&psum[g * 128 + c * 4 + 2], s.z);
    atomicAdd(&psum[g * 128 + c * 4 + 3], s.w);
    atomicMax((int*)&pmax[g * 128 + c * 4 + 0], __float_as_int(m.x));
    atomicMax((int*)&pmax[g * 128 + c * 4 + 1], __float_as_int(m.y));
    atomicMax((int*)&pmax[g * 128 + c * 4 + 2], __float_as_int(m.z));
    atomicMax((int*)&pmax[g * 128 + c * 4 + 3], __float_as_int(m.w));
    if (c == 0) atomicAdd(&pcnt[g], (float)cnt);
}

__global__ void k_final(const float* __restrict__ psum, const float* __restrict__ pmax,
                        const float* __restrict__ pcnt, const float* __restrict__ Wp,
                        const float* __restrict__ bp, float* __restrict__ out) {
    int t = blockIdx.x * blockDim.x + threadIdx.x;
    if (t >= N_GRAPHS * 256) return;
    int g = t >> 8, j = t & 255;
    float inv = 1.0f / fmaxf(pcnt[g], 1.0f);
    float acc = bp[j];
#pragma unroll 4
    for (int k = 0; k < 128; k++) acc += (psum[g * 128 + k] * inv) * Wp[k * 256 + j];
#pragma unroll 4
    for (int k = 0; k < 128; k++) acc += pmax[g * 128 + k] * Wp[(128 + k) * 256 + j];
    out[t] = fmaxf(acc, 0.f);
}

extern "C" void kernel_launch(void* const* d_in, const int* in_sizes, int n_in,
                              void* d_out, int out_size, void* d_ws, size_t ws_size,
                              hipStream_t stream) {
    const int N = N_NODES, E = N_EDGES;
    const float* x    = (const float*)d_in[0];
    const int*   ei   = (const int*)d_in[1];
    const int*   src  = ei;
    const int*   dst  = ei + E;
    const int*   batch= (const int*)d_in[2];
    const float* W_in = (const float*)d_in[3];
    const float* b_in = (const float*)d_in[4];
    const float* W1   = (const float*)d_in[5];
    const float* b1   = (const float*)d_in[6];
    const float* W2   = (const float*)d_in[7];
    const float* b2   = (const float*)d_in[8];
    const float* Wp   = (const float*)d_in[9];
    const float* bp   = (const float*)d_in[10];
    float* out = (float*)d_out;

    char* p = (char*)d_ws;
    int* counts  = (int*)p;      p += CMAT * 4;
    int* cbase   = (int*)p;      p += CMAT * 4;
    int* bsum    = (int*)p;      p += 256 * 4;
    int* bscan   = (int*)p;      p += 256 * 4;
    int* row_ptr = (int*)p;      p += (N_PAD + 64) * 4;
    int* col     = (int*)p;      p += (size_t)N_EDGES * 4;
    float* dinv  = (float*)p;    p += N_PAD * 4;
    float* A     = (float*)p;    p += (size_t)N_PAD * 128 * 4;  // fp16 g OR fp32 h2
    float* B     = (float*)p;    p += (size_t)N_PAD * 128 * 4;  // fp32 gather output s
    float* psum  = (float*)p;    p += N_GRAPHS * 128 * 4;
    float* pmax  = (float*)p;    p += N_GRAPHS * 128 * 4;
    float* pcnt  = (float*)p;
    __half* Ah = (__half*)A;
    unsigned long long* esort = (unsigned long long*)B;  // alias: dead before first B write

    const int TB = 256;
    dim3 blk(TB);
    int gN16 = (N * 16 + TB - 1) / TB;
    int gGemm = (N + 31) / 32;

    // CSR build: two-level counting sort, zero global atomics
    k_coarse_hist<<<CB, blk, 0, stream>>>(dst, counts);
    k_block_sum<<<SCAN_NB, blk, 0, stream>>>(counts, bsum, CMAT);
    k_bsum_scan<<<1, blk, 0, stream>>>(bsum, bscan, SCAN_NB);
    k_scan_write<<<SCAN_NB, blk, 0, stream>>>(counts, bscan, cbase, CMAT);
    k_coarse_scatter<<<CB, blk, 0, stream>>>(src, dst, cbase, esort);
    k_fine_fill<<<NBUCKET, blk, 0, stream>>>(esort, cbase, col, row_ptr, dinv);

    // g0 = fp16(dinv * (x@W_in + b_in))   [N,64] in Ah
    k_proj_scale<<<gN16, blk, 0, stream>>>(x, W_in, b_in, dinv, Ah, N);

    // layer 1: s0 = gather(g0) in B (fp32) ; g1 = fp16(dinv*relu(dinv*(s0@W1)+b1)) in Ah
    k_gather_h<64><<<(N * 8 + TB - 1) / TB, blk, 0, stream>>>((const H8*)Ah, row_ptr, col, B, N);
    k_lin_tiled<64, true><<<gGemm, blk, 0, stream>>>(B, W1, b1, dinv, Ah, N);

    // layer 2: s1 = gather(g1) in B ; h2 = relu(dinv*(s1@W2)+b2) fp32 in A
    k_gather_h<128><<<(N * 16 + TB - 1) / TB, blk, 0, stream>>>((const H8*)Ah, row_ptr, col, B, N);
    k_lin_tiled<128, false><<<gGemm, blk, 0, stream>>>(B, W2, b2, dinv, A, N);

    // pooling
    k_pool_init<<<(N_GRAPHS * 128 + TB - 1) / TB, blk, 0, stream>>>(psum, pmax, pcnt);
    int chunks = (N + 63) / 64;
    k_pool<<<(chunks * 32 + TB - 1) / TB, blk, 0, stream>>>(A, batch, psum, pmax, pcnt, N);

    // final MLP
    k_final<<<(N_GRAPHS * 256 + TB - 1) / TB, blk, 0, stream>>>(psum, pmax, pcnt, Wp, bp, out);
}

// Round 7
// 283.636 us; speedup vs baseline: 4.1556x; 1.0034x over previous
//
#include <hip/hip_runtime.h>
#include <hip/hip_fp16.h>

#define N_NODES 50000
#define N_EDGES 800000
#define N_GRAPHS 64
#define N_PAD 50048

#define CB 256                              // coarse-pass blocks
#define EPB (N_EDGES / CB)                  // 3125 edges per block (exact)
#define NBUCKET ((N_NODES + 255) / 256)     // 196 coarse buckets (dst>>8)
#define CMAT (NBUCKET * CB)                 // 50176 count-matrix entries
#define SCAN_NB ((CMAT + 255) / 256)        // 196 scan blocks

// ---------------- CSR build: two-level LDS counting sort ----------------

__global__ __launch_bounds__(256) void k_coarse_hist(const int* __restrict__ dst,
                                                     int* __restrict__ counts) {
    __shared__ int hist[NBUCKET];
    int t = threadIdx.x, b = blockIdx.x;
    for (int i = t; i < NBUCKET; i += 256) hist[i] = 0;
    __syncthreads();
    int e0 = b * EPB;
    for (int e = e0 + t; e < e0 + EPB; e += 256)
        atomicAdd(&hist[dst[e] >> 8], 1);
    __syncthreads();
    for (int i = t; i < NBUCKET; i += 256)
        counts[i * CB + b] = hist[i];
}

__global__ void k_block_sum(const int* __restrict__ v, int* __restrict__ bsum, int len) {
    __shared__ int sh[256];
    int t = threadIdx.x;
    int i = blockIdx.x * 256 + t;
    sh[t] = (i < len) ? v[i] : 0;
    __syncthreads();
    for (int off = 128; off > 0; off >>= 1) {
        if (t < off) sh[t] += sh[t + off];
        __syncthreads();
    }
    if (t == 0) bsum[blockIdx.x] = sh[0];
}

__global__ void k_bsum_scan(const int* __restrict__ bsum, int* __restrict__ bscan, int nb) {
    __shared__ int sh[256];
    int t = threadIdx.x;
    int v = (t < nb) ? bsum[t] : 0;
    sh[t] = v;
    __syncthreads();
    for (int off = 1; off < 256; off <<= 1) {
        int u = (t >= off) ? sh[t - off] : 0;
        __syncthreads();
        sh[t] += u;
        __syncthreads();
    }
    if (t < nb) bscan[t] = sh[t] - v;  // exclusive
}

__global__ void k_scan_write(const int* __restrict__ v, const int* __restrict__ bscan,
                             int* __restrict__ outx, int len) {
    __shared__ int sh[256];
    int t = threadIdx.x;
    int i = blockIdx.x * 256 + t;
    int x = (i < len) ? v[i] : 0;
    sh[t] = x;
    __syncthreads();
    for (int off = 1; off < 256; off <<= 1) {
        int u = (t >= off) ? sh[t - off] : 0;
        __syncthreads();
        sh[t] += u;
        __syncthreads();
    }
    if (i < len) outx[i] = sh[t] - x + bscan[blockIdx.x];
}

__global__ __launch_bounds__(256) void k_coarse_scatter(
        const int* __restrict__ src, const int* __restrict__ dst,
        const int* __restrict__ cbase, unsigned long long* __restrict__ esort) {
    __shared__ int cur[NBUCKET];
    int t = threadIdx.x, b = blockIdx.x;
    for (int i = t; i < NBUCKET; i += 256) cur[i] = cbase[i * CB + b];
    __syncthreads();
    int e0 = b * EPB;
    for (int e = e0 + t; e < e0 + EPB; e += 256) {
        int d = dst[e];
        int slot = atomicAdd(&cur[d >> 8], 1);
        esort[slot] = ((unsigned long long)(unsigned)d << 32) | (unsigned)src[e];
    }
}

__global__ __launch_bounds__(256) void k_fine_fill(
        const unsigned long long* __restrict__ esort, const int* __restrict__ cbase,
        int* __restrict__ col, int* __restrict__ row_ptr, float* __restrict__ dinv) {
    __shared__ int hist[256];
    __shared__ int sc[256];
    __shared__ int cur[256];
    __shared__ int range[2];
    int t = threadIdx.x, b = blockIdx.x;
    hist[t] = 0;
    if (t == 0) {
        range[0] = cbase[b * CB];
        range[1] = (b + 1 < NBUCKET) ? cbase[(b + 1) * CB] : N_EDGES;
    }
    __syncthreads();
    int base = range[0], end = range[1];
    for (int e = base + t; e < end; e += 256)
        atomicAdd(&hist[(int)(esort[e] >> 32) & 255], 1);
    __syncthreads();
    int v = hist[t];
    sc[t] = v;
    __syncthreads();
    for (int off = 1; off < 256; off <<= 1) {
        int u = (t >= off) ? sc[t - off] : 0;
        __syncthreads();
        sc[t] += u;
        __syncthreads();
    }
    int start = base + sc[t] - v;
    cur[t] = start;
    int node = b * 256 + t;
    if (node < N_NODES) {
        row_ptr[node] = start;
        dinv[node] = rsqrtf((float)(v + 1));  // +1 self-loop
    }
    if (b == 0 && t == 0) row_ptr[N_NODES] = N_EDGES;
    __syncthreads();
    for (int e = base + t; e < end; e += 256) {
        unsigned long long pk = esort[e];
        int slot = atomicAdd(&cur[(int)(pk >> 32) & 255], 1);
        col[slot] = (int)(pk & 0xffffffffu);
    }
}

// ---------------- dense ----------------

__global__ void k_proj_scale(const float* __restrict__ x, const float* __restrict__ W,
                             const float* __restrict__ b, const float* __restrict__ dinv,
                             __half* __restrict__ g0, int n) {
    int t = blockIdx.x * blockDim.x + threadIdx.x;
    if (t >= n * 16) return;
    int i = t >> 4, jq = t & 15;
    float4 acc = *(const float4*)&b[jq * 4];
#pragma unroll
    for (int k = 0; k < 6; k++) {
        float xv = x[i * 6 + k];
        float4 w = *(const float4*)&W[k * 64 + jq * 4];
        acc.x += xv * w.x; acc.y += xv * w.y; acc.z += xv * w.z; acc.w += xv * w.w;
    }
    float di = dinv[i];
    union { __half2 h[2]; uint2 u; } pk;
    pk.h[0] = __floats2half2_rn(acc.x * di, acc.y * di);
    pk.h[1] = __floats2half2_rn(acc.z * di, acc.w * di);
    *(uint2*)&g0[(size_t)i * 64 + jq * 4] = pk.u;
}

struct H8 { __half2 a, b, c, d; };

template <int C>
__global__ void k_gather_h(const H8* __restrict__ g, const int* __restrict__ row_ptr,
                           const int* __restrict__ col, float* __restrict__ s_out, int n) {
    constexpr int CO = C / 8;
    int t = blockIdx.x * blockDim.x + threadIdx.x;
    if (t >= n * CO) return;
    int i = t / CO;
    int c = t & (CO - 1);
    float acc[8] = {};
    auto addv = [&](H8 v) {
        float2 f;
        f = __half22float2(v.a); acc[0] += f.x; acc[1] += f.y;
        f = __half22float2(v.b); acc[2] += f.x; acc[3] += f.y;
        f = __half22float2(v.c); acc[4] += f.x; acc[5] += f.y;
        f = __half22float2(v.d); acc[6] += f.x; acc[7] += f.y;
    };
    addv(g[(size_t)i * CO + c]);
    int e = row_ptr[i], e1 = row_ptr[i + 1];
    for (; e + 1 < e1; e += 2) {
        H8 v0 = g[(size_t)col[e] * CO + c];
        H8 v1 = g[(size_t)col[e + 1] * CO + c];
        addv(v0);
        addv(v1);
    }
    if (e < e1) addv(g[(size_t)col[e] * CO + c]);
    float4* o = (float4*)&s_out[(size_t)i * C + c * 8];
    o[0] = make_float4(acc[0], acc[1], acc[2], acc[3]);
    o[1] = make_float4(acc[4], acc[5], acc[6], acc[7]);
}

// Tiled GEMM: out[N,128] = epilogue(s[N,K] @ W[K,128])
// LDS chunked: 32 K-rows at a time (16 KB) so LDS doesn't cap occupancy.
// block: 32 rows x 128 cols, 256 threads, thread = 4 rows x 4 cols
template <int K, bool HALF_OUT>
__global__ __launch_bounds__(256) void k_lin_tiled(
        const float* __restrict__ s, const float* __restrict__ W,
        const float* __restrict__ b, const float* __restrict__ dinv,
        void* __restrict__ outp, int n) {
    constexpr int KC = 32;
    __shared__ float Wlds[KC * 128];
    int t = threadIdx.x;

    int cq = t & 31;
    int rg = t >> 5;
    int row0 = blockIdx.x * 32 + rg * 4;
    int r0 = min(row0 + 0, n - 1);
    int r1 = min(row0 + 1, n - 1);
    int r2 = min(row0 + 2, n - 1);
    int r3 = min(row0 + 3, n - 1);
    const float* sr0 = s + (size_t)r0 * K;
    const float* sr1 = s + (size_t)r1 * K;
    const float* sr2 = s + (size_t)r2 * K;
    const float* sr3 = s + (size_t)r3 * K;

    float4 acc[4] = {};
    for (int k0 = 0; k0 < K; k0 += KC) {
        __syncthreads();  // protect Wlds from previous chunk's readers
#pragma unroll
        for (int idx = t * 4; idx < KC * 128; idx += 256 * 4)
            *(float4*)&Wlds[idx] = *(const float4*)&W[k0 * 128 + idx];
        __syncthreads();
#pragma unroll
        for (int k = 0; k < KC; k += 4) {
            float4 a0 = *(const float4*)&sr0[k0 + k];
            float4 a1 = *(const float4*)&sr1[k0 + k];
            float4 a2 = *(const float4*)&sr2[k0 + k];
            float4 a3 = *(const float4*)&sr3[k0 + k];
#pragma unroll
            for (int kk = 0; kk < 4; kk++) {
                float4 w = *(float4*)&Wlds[(k + kk) * 128 + cq * 4];
                float av0 = kk == 0 ? a0.x : kk == 1 ? a0.y : kk == 2 ? a0.z : a0.w;
                float av1 = kk == 0 ? a1.x : kk == 1 ? a1.y : kk == 2 ? a1.z : a1.w;
                float av2 = kk == 0 ? a2.x : kk == 1 ? a2.y : kk == 2 ? a2.z : a2.w;
                float av3 = kk == 0 ? a3.x : kk == 1 ? a3.y : kk == 2 ? a3.z : a3.w;
                acc[0].x += av0 * w.x; acc[0].y += av0 * w.y; acc[0].z += av0 * w.z; acc[0].w += av0 * w.w;
                acc[1].x += av1 * w.x; acc[1].y += av1 * w.y; acc[1].z += av1 * w.z; acc[1].w += av1 * w.w;
                acc[2].x += av2 * w.x; acc[2].y += av2 * w.y; acc[2].z += av2 * w.z; acc[2].w += av2 * w.w;
                acc[3].x += av3 * w.x; acc[3].y += av3 * w.y; acc[3].z += av3 * w.z; acc[3].w += av3 * w.w;
            }
        }
    }

    float4 bb = *(const float4*)&b[cq * 4];
#pragma unroll
    for (int r = 0; r < 4; r++) {
        int row = row0 + r;
        if (row < n) {
            float di = dinv[row];
            float4 v;
            v.x = fmaxf(di * acc[r].x + bb.x, 0.f);
            v.y = fmaxf(di * acc[r].y + bb.y, 0.f);
            v.z = fmaxf(di * acc[r].z + bb.z, 0.f);
            v.w = fmaxf(di * acc[r].w + bb.w, 0.f);
            if (HALF_OUT) {
                __half* out = (__half*)outp;
                union { __half2 h[2]; uint2 u; } pk;
                pk.h[0] = __floats2half2_rn(v.x * di, v.y * di);
                pk.h[1] = __floats2half2_rn(v.z * di, v.w * di);
                *(uint2*)&out[(size_t)row * 128 + cq * 4] = pk.u;
            } else {
                float* out = (float*)outp;
                *(float4*)&out[(size_t)row * 128 + cq * 4] = v;
            }
        }
    }
}

// ---------------- pooling + final ----------------

__global__ void k_pool_init(float* psum, float* pmax, float* pcnt) {
    int t = blockIdx.x * blockDim.x + threadIdx.x;
    if (t < N_GRAPHS * 128) { psum[t] = 0.f; pmax[t] = 0.f; }
    if (t < N_GRAPHS) pcnt[t] = 0.f;
}

__global__ void k_pool(const float* __restrict__ h, const int* __restrict__ batch,
                       float* psum, float* pmax, float* pcnt, int n) {
    const int CH = 64;
    int t = blockIdx.x * blockDim.x + threadIdx.x;
    int c = t & 31;
    int chunk = t >> 5;
    int i0 = chunk * CH;
    if (i0 >= n) return;
    int i1 = min(i0 + CH, n);
    const float4* h4 = (const float4*)h;
    float4 s = {0, 0, 0, 0}, m = {0, 0, 0, 0};
    int cnt = 0;
    int g = batch[i0];
    for (int i = i0; i < i1; i++) {
        int gi = batch[i];
        if (gi != g) {
            atomicAdd(&psum[g * 128 + c * 4 + 0], s.x);
            atomicAdd(&psum[g * 128 + c * 4 + 1], s.y);
            atomicAdd(&psum[g * 128 + c * 4 + 2], s.z);
            atomicAdd(&psum[g * 128 + c * 4 + 3], s.w);
            atomicMax((int*)&pmax[g * 128 + c * 4 + 0], __float_as_int(m.x));
            atomicMax((int*)&pmax[g * 128 + c * 4 + 1], __float_as_int(m.y));
            atomicMax((int*)&pmax[g * 128 + c * 4 + 2], __float_as_int(m.z));
            atomicMax((int*)&pmax[g * 128 + c * 4 + 3], __float_as_int(m.w));
            if (c == 0) atomicAdd(&pcnt[g], (float)cnt);
            s = {0, 0, 0, 0}; m = {0, 0, 0, 0}; cnt = 0; g = gi;
        }
        float4 v = h4[(size_t)i * 32 + c];
        s.x += v.x; s.y += v.y; s.z += v.z; s.w += v.w;
        m.x = fmaxf(m.x, v.x); m.y = fmaxf(m.y, v.y);
        m.z = fmaxf(m.z, v.z); m.w = fmaxf(m.w, v.w);
        cnt++;
    }
    atomicAdd(&psum[g * 128 + c * 4 + 0], s.x);
    atomicAdd(&psum[g * 128 + c * 4 + 1], s.y);
    atomicAdd(&psum[g * 128 + c * 4 + 2], s.z);
    atomicAdd(&psum[g * 128 + c * 4 + 3], s.w);
    atomicMax((int*)&pmax[g * 128 + c * 4 + 0], __float_as_int(m.x));
    atomicMax((int*)&pmax[g * 128 + c * 4 + 1], __float_as_int(m.y));
    atomicMax((int*)&pmax[g * 128 + c * 4 + 2], __float_as_int(m.z));
    atomicMax((int*)&pmax[g * 128 + c * 4 + 3], __float_as_int(m.w));
    if (c == 0) atomicAdd(&pcnt[g], (float)cnt);
}

__global__ void k_final(const float* __restrict__ psum, const float* __restrict__ pmax,
                        const float* __restrict__ pcnt, const float* __restrict__ Wp,
                        const float* __restrict__ bp, float* __restrict__ out) {
    int t = blockIdx.x * blockDim.x + threadIdx.x;
    if (t >= N_GRAPHS * 256) return;
    int g = t >> 8, j = t & 255;
    float inv = 1.0f / fmaxf(pcnt[g], 1.0f);
    float acc = bp[j];
#pragma unroll 4
    for (int k = 0; k < 128; k++) acc += (psum[g * 128 + k] * inv) * Wp[k * 256 + j];
#pragma unroll 4
    for (int k = 0; k < 128; k++) acc += pmax[g * 128 + k] * Wp[(128 + k) * 256 + j];
    out[t] = fmaxf(acc, 0.f);
}

extern "C" void kernel_launch(void* const* d_in, const int* in_sizes, int n_in,
                              void* d_out, int out_size, void* d_ws, size_t ws_size,
                              hipStream_t stream) {
    const int N = N_NODES, E = N_EDGES;
    const float* x    = (const float*)d_in[0];
    const int*   ei   = (const int*)d_in[1];
    const int*   src  = ei;
    const int*   dst  = ei + E;
    const int*   batch= (const int*)d_in[2];
    const float* W_in = (const float*)d_in[3];
    const float* b_in = (const float*)d_in[4];
    const float* W1   = (const float*)d_in[5];
    const float* b1   = (const float*)d_in[6];
    const float* W2   = (const float*)d_in[7];
    const float* b2   = (const float*)d_in[8];
    const float* Wp   = (const float*)d_in[9];
    const float* bp   = (const float*)d_in[10];
    float* out = (float*)d_out;

    char* p = (char*)d_ws;
    int* counts  = (int*)p;      p += CMAT * 4;
    int* cbase   = (int*)p;      p += CMAT * 4;
    int* bsum    = (int*)p;      p += 256 * 4;
    int* bscan   = (int*)p;      p += 256 * 4;
    int* row_ptr = (int*)p;      p += (N_PAD + 64) * 4;
    int* col     = (int*)p;      p += (size_t)N_EDGES * 4;
    float* dinv  = (float*)p;    p += N_PAD * 4;
    float* A     = (float*)p;    p += (size_t)N_PAD * 128 * 4;  // fp16 g OR fp32 h2
    float* B     = (float*)p;    p += (size_t)N_PAD * 128 * 4;  // fp32 gather output s
    float* psum  = (float*)p;    p += N_GRAPHS * 128 * 4;
    float* pmax  = (float*)p;    p += N_GRAPHS * 128 * 4;
    float* pcnt  = (float*)p;
    __half* Ah = (__half*)A;
    unsigned long long* esort = (unsigned long long*)B;  // alias: dead before first B write

    const int TB = 256;
    dim3 blk(TB);
    int gN16 = (N * 16 + TB - 1) / TB;
    int gGemm = (N + 31) / 32;

    // CSR build: two-level counting sort, zero global atomics
    k_coarse_hist<<<CB, blk, 0, stream>>>(dst, counts);
    k_block_sum<<<SCAN_NB, blk, 0, stream>>>(counts, bsum, CMAT);
    k_bsum_scan<<<1, blk, 0, stream>>>(bsum, bscan, SCAN_NB);
    k_scan_write<<<SCAN_NB, blk, 0, stream>>>(counts, bscan, cbase, CMAT);
    k_coarse_scatter<<<CB, blk, 0, stream>>>(src, dst, cbase, esort);
    k_fine_fill<<<NBUCKET, blk, 0, stream>>>(esort, cbase, col, row_ptr, dinv);

    // g0 = fp16(dinv * (x@W_in + b_in))   [N,64] in Ah
    k_proj_scale<<<gN16, blk, 0, stream>>>(x, W_in, b_in, dinv, Ah, N);

    // layer 1
    k_gather_h<64><<<(N * 8 + TB - 1) / TB, blk, 0, stream>>>((const H8*)Ah, row_ptr, col, B, N);
    k_lin_tiled<64, true><<<gGemm, blk, 0, stream>>>(B, W1, b1, dinv, Ah, N);

    // layer 2
    k_gather_h<128><<<(N * 16 + TB - 1) / TB, blk, 0, stream>>>((const H8*)Ah, row_ptr, col, B, N);
    k_lin_tiled<128, false><<<gGemm, blk, 0, stream>>>(B, W2, b2, dinv, A, N);

    // pooling
    k_pool_init<<<(N_GRAPHS * 128 + TB - 1) / TB, blk, 0, stream>>>(psum, pmax, pcnt);
    int chunks = (N + 63) / 64;
    k_pool<<<(chunks * 32 + TB - 1) / TB, blk, 0, stream>>>(A, batch, psum, pmax, pcnt, N);

    // final MLP
    k_final<<<(N_GRAPHS * 256 + TB - 1) / TB, blk, 0, stream>>>(psum, pmax, pcnt, Wp, bp, out);
}

// Round 8
// 244.020 us; speedup vs baseline: 4.8302x; 1.1624x over previous
//
#include <hip/hip_runtime.h>
#include <hip/hip_fp16.h>

#define N_NODES 50000
#define N_EDGES 800000
#define N_GRAPHS 64
#define N_PAD 50048

#define CB 256                              // coarse-pass blocks
#define EPB (N_EDGES / CB)                  // 3125 edges per block (exact)
#define NBUCKET ((N_NODES + 255) / 256)     // 196 coarse buckets (dst>>8)
#define CMAT (NBUCKET * CB)                 // 50176 count-matrix entries
#define SCAN_NB ((CMAT + 255) / 256)        // 196 scan blocks

typedef _Float16 f16x8 __attribute__((ext_vector_type(8)));
typedef float f32x4 __attribute__((ext_vector_type(4)));

// ---------------- CSR build: two-level LDS counting sort ----------------

__global__ __launch_bounds__(256) void k_coarse_hist(const int* __restrict__ dst,
                                                     int* __restrict__ counts) {
    __shared__ int hist[NBUCKET];
    int t = threadIdx.x, b = blockIdx.x;
    for (int i = t; i < NBUCKET; i += 256) hist[i] = 0;
    __syncthreads();
    int e0 = b * EPB;
    for (int e = e0 + t; e < e0 + EPB; e += 256)
        atomicAdd(&hist[dst[e] >> 8], 1);
    __syncthreads();
    for (int i = t; i < NBUCKET; i += 256)
        counts[i * CB + b] = hist[i];
}

__global__ void k_block_sum(const int* __restrict__ v, int* __restrict__ bsum, int len) {
    __shared__ int sh[256];
    int t = threadIdx.x;
    int i = blockIdx.x * 256 + t;
    sh[t] = (i < len) ? v[i] : 0;
    __syncthreads();
    for (int off = 128; off > 0; off >>= 1) {
        if (t < off) sh[t] += sh[t + off];
        __syncthreads();
    }
    if (t == 0) bsum[blockIdx.x] = sh[0];
}

__global__ void k_bsum_scan(const int* __restrict__ bsum, int* __restrict__ bscan, int nb) {
    __shared__ int sh[256];
    int t = threadIdx.x;
    int v = (t < nb) ? bsum[t] : 0;
    sh[t] = v;
    __syncthreads();
    for (int off = 1; off < 256; off <<= 1) {
        int u = (t >= off) ? sh[t - off] : 0;
        __syncthreads();
        sh[t] += u;
        __syncthreads();
    }
    if (t < nb) bscan[t] = sh[t] - v;  // exclusive
}

__global__ void k_scan_write(const int* __restrict__ v, const int* __restrict__ bscan,
                             int* __restrict__ outx, int len) {
    __shared__ int sh[256];
    int t = threadIdx.x;
    int i = blockIdx.x * 256 + t;
    int x = (i < len) ? v[i] : 0;
    sh[t] = x;
    __syncthreads();
    for (int off = 1; off < 256; off <<= 1) {
        int u = (t >= off) ? sh[t - off] : 0;
        __syncthreads();
        sh[t] += u;
        __syncthreads();
    }
    if (i < len) outx[i] = sh[t] - x + bscan[blockIdx.x];
}

__global__ __launch_bounds__(256) void k_coarse_scatter(
        const int* __restrict__ src, const int* __restrict__ dst,
        const int* __restrict__ cbase, unsigned long long* __restrict__ esort) {
    __shared__ int cur[NBUCKET];
    int t = threadIdx.x, b = blockIdx.x;
    for (int i = t; i < NBUCKET; i += 256) cur[i] = cbase[i * CB + b];
    __syncthreads();
    int e0 = b * EPB;
    for (int e = e0 + t; e < e0 + EPB; e += 256) {
        int d = dst[e];
        int slot = atomicAdd(&cur[d >> 8], 1);
        esort[slot] = ((unsigned long long)(unsigned)d << 32) | (unsigned)src[e];
    }
}

__global__ __launch_bounds__(256) void k_fine_fill(
        const unsigned long long* __restrict__ esort, const int* __restrict__ cbase,
        int* __restrict__ col, int* __restrict__ row_ptr, float* __restrict__ dinv) {
    __shared__ int hist[256];
    __shared__ int sc[256];
    __shared__ int cur[256];
    __shared__ int range[2];
    int t = threadIdx.x, b = blockIdx.x;
    hist[t] = 0;
    if (t == 0) {
        range[0] = cbase[b * CB];
        range[1] = (b + 1 < NBUCKET) ? cbase[(b + 1) * CB] : N_EDGES;
    }
    __syncthreads();
    int base = range[0], end = range[1];
    for (int e = base + t; e < end; e += 256)
        atomicAdd(&hist[(int)(esort[e] >> 32) & 255], 1);
    __syncthreads();
    int v = hist[t];
    sc[t] = v;
    __syncthreads();
    for (int off = 1; off < 256; off <<= 1) {
        int u = (t >= off) ? sc[t - off] : 0;
        __syncthreads();
        sc[t] += u;
        __syncthreads();
    }
    int start = base + sc[t] - v;
    cur[t] = start;
    int node = b * 256 + t;
    if (node < N_NODES) {
        row_ptr[node] = start;
        dinv[node] = rsqrtf((float)(v + 1));  // +1 self-loop
    }
    if (b == 0 && t == 0) row_ptr[N_NODES] = N_EDGES;
    __syncthreads();
    for (int e = base + t; e < end; e += 256) {
        unsigned long long pk = esort[e];
        int slot = atomicAdd(&cur[(int)(pk >> 32) & 255], 1);
        col[slot] = (int)(pk & 0xffffffffu);
    }
}

// ---------------- weight prep: Wt_h[n*K + k] = fp16(W[k*128 + n]) ----------------

__global__ void k_prep_w(const float* __restrict__ W, _Float16* __restrict__ Wt, int K) {
    int idx = blockIdx.x * blockDim.x + threadIdx.x;
    if (idx >= 128 * K) return;
    int n = idx / K, k = idx - n * K;
    Wt[idx] = (_Float16)W[k * 128 + n];
}

// ---------------- dense ----------------

__global__ void k_proj_scale(const float* __restrict__ x, const float* __restrict__ W,
                             const float* __restrict__ b, const float* __restrict__ dinv,
                             __half* __restrict__ g0, int n) {
    int t = blockIdx.x * blockDim.x + threadIdx.x;
    if (t >= n * 16) return;
    int i = t >> 4, jq = t & 15;
    float4 acc = *(const float4*)&b[jq * 4];
#pragma unroll
    for (int k = 0; k < 6; k++) {
        float xv = x[i * 6 + k];
        float4 w = *(const float4*)&W[k * 64 + jq * 4];
        acc.x += xv * w.x; acc.y += xv * w.y; acc.z += xv * w.z; acc.w += xv * w.w;
    }
    float di = dinv[i];
    union { __half2 h[2]; uint2 u; } pk;
    pk.h[0] = __floats2half2_rn(acc.x * di, acc.y * di);
    pk.h[1] = __floats2half2_rn(acc.z * di, acc.w * di);
    *(uint2*)&g0[(size_t)i * 64 + jq * 4] = pk.u;
}

struct H8 { __half2 a, b, c, d; };

// fp16 gather -> fp16 output (fp32 accumulate in registers)
template <int C>
__global__ void k_gather_h(const H8* __restrict__ g, const int* __restrict__ row_ptr,
                           const int* __restrict__ col, _Float16* __restrict__ s_out, int n) {
    constexpr int CO = C / 8;
    int t = blockIdx.x * blockDim.x + threadIdx.x;
    if (t >= n * CO) return;
    int i = t / CO;
    int c = t & (CO - 1);
    float acc[8] = {};
    auto addv = [&](H8 v) {
        float2 f;
        f = __half22float2(v.a); acc[0] += f.x; acc[1] += f.y;
        f = __half22float2(v.b); acc[2] += f.x; acc[3] += f.y;
        f = __half22float2(v.c); acc[4] += f.x; acc[5] += f.y;
        f = __half22float2(v.d); acc[6] += f.x; acc[7] += f.y;
    };
    addv(g[(size_t)i * CO + c]);
    int e = row_ptr[i], e1 = row_ptr[i + 1];
    for (; e + 1 < e1; e += 2) {
        H8 v0 = g[(size_t)col[e] * CO + c];
        H8 v1 = g[(size_t)col[e + 1] * CO + c];
        addv(v0);
        addv(v1);
    }
    if (e < e1) addv(g[(size_t)col[e] * CO + c]);
    f16x8 o;
#pragma unroll
    for (int j = 0; j < 8; j++) o[j] = (_Float16)acc[j];
    *(f16x8*)&s_out[(size_t)i * C + c * 8] = o;
}

// MFMA GEMM: out[N,128] = epilogue(s_h[N,K] @ W[K,128]), fp16 in, fp32 acc.
// block = 4 waves; wave = 16 rows x 128 cols (8 tiles of 16x16); K-loop step 32.
// B operand from LDS-staged Wt (n-major, +8 pad to avoid bank conflicts).
template <int K, bool HALF_OUT>
__global__ __launch_bounds__(256) void k_lin_mfma(
        const _Float16* __restrict__ s_h, const _Float16* __restrict__ Wt_h,
        const float* __restrict__ b, const float* __restrict__ dinv,
        void* __restrict__ outp, int n) {
    constexpr int KP = K + 8;
    __shared__ __align__(16) _Float16 Wl[128 * KP];
    int t = threadIdx.x;
    constexpr int CH = 128 * K / 8;  // 16B chunks
    for (int c = t; c < CH; c += 256) {
        int row = c / (K / 8), off = c - row * (K / 8);
        *(f16x8*)&Wl[row * KP + off * 8] = *(const f16x8*)&Wt_h[row * K + off * 8];
    }
    __syncthreads();

    int wave = t >> 6;
    int lane = t & 63;
    int m = lane & 15;        // A-row / C-col within tile
    int quad = lane >> 4;     // k-chunk selector / C-row group
    int wrow0 = blockIdx.x * 64 + wave * 16;

    const _Float16* ap = s_h + (size_t)wrow0 * K + (size_t)m * K + quad * 8;

    f32x4 acc[8] = {};
#pragma unroll
    for (int k0 = 0; k0 < K; k0 += 32) {
        f16x8 a = *(const f16x8*)(ap + k0);
#pragma unroll
        for (int nt = 0; nt < 8; nt++) {
            f16x8 bw = *(const f16x8*)&Wl[(nt * 16 + m) * KP + k0 + quad * 8];
            acc[nt] = __builtin_amdgcn_mfma_f32_16x16x32_f16(a, bw, acc[nt], 0, 0, 0);
        }
    }

#pragma unroll
    for (int r = 0; r < 4; r++) {
        int row = wrow0 + quad * 4 + r;
        if (row < n) {
            float di = dinv[row];
#pragma unroll
            for (int nt = 0; nt < 8; nt++) {
                int colb = nt * 16 + m;
                float v = fmaxf(di * acc[nt][r] + b[colb], 0.f);
                if (HALF_OUT)
                    ((_Float16*)outp)[(size_t)row * 128 + colb] = (_Float16)(v * di);
                else
                    ((float*)outp)[(size_t)row * 128 + colb] = v;
            }
        }
    }
}

// ---------------- pooling + final ----------------

__global__ void k_pool_init(float* psum, float* pmax, float* pcnt) {
    int t = blockIdx.x * blockDim.x + threadIdx.x;
    if (t < N_GRAPHS * 128) { psum[t] = 0.f; pmax[t] = 0.f; }
    if (t < N_GRAPHS) pcnt[t] = 0.f;
}

__global__ void k_pool(const float* __restrict__ h, const int* __restrict__ batch,
                       float* psum, float* pmax, float* pcnt, int n) {
    const int CH = 64;
    int t = blockIdx.x * blockDim.x + threadIdx.x;
    int c = t & 31;
    int chunk = t >> 5;
    int i0 = chunk * CH;
    if (i0 >= n) return;
    int i1 = min(i0 + CH, n);
    const float4* h4 = (const float4*)h;
    float4 s = {0, 0, 0, 0}, m = {0, 0, 0, 0};
    int cnt = 0;
    int g = batch[i0];
    for (int i = i0; i < i1; i++) {
        int gi = batch[i];
        if (gi != g) {
            atomicAdd(&psum[g * 128 + c * 4 + 0], s.x);
            atomicAdd(&psum[g * 128 + c * 4 + 1], s.y);
            atomicAdd(&psum[g * 128 + c * 4 + 2], s.z);
            atomicAdd(&psum[g * 128 + c * 4 + 3], s.w);
            atomicMax((int*)&pmax[g * 128 + c * 4 + 0], __float_as_int(m.x));
            atomicMax((int*)&pmax[g * 128 + c * 4 + 1], __float_as_int(m.y));
            atomicMax((int*)&pmax[g * 128 + c * 4 + 2], __float_as_int(m.z));
            atomicMax((int*)&pmax[g * 128 + c * 4 + 3], __float_as_int(m.w));
            if (c == 0) atomicAdd(&pcnt[g], (float)cnt);
            s = {0, 0, 0, 0}; m = {0, 0, 0, 0}; cnt = 0; g = gi;
        }
        float4 v = h4[(size_t)i * 32 + c];
        s.x += v.x; s.y += v.y; s.z += v.z; s.w += v.w;
        m.x = fmaxf(m.x, v.x); m.y = fmaxf(m.y, v.y);
        m.z = fmaxf(m.z, v.z); m.w = fmaxf(m.w, v.w);
        cnt++;
    }
    atomicAdd(&psum[g * 128 + c * 4 + 0], s.x);
    atomicAdd(&psum[g * 128 + c * 4 + 1], s.y);
    atomicAdd(&psum[g * 128 + c * 4 + 2], s.z);
    atomicAdd(&psum[g * 128 + c * 4 + 3], s.w);
    atomicMax((int*)&pmax[g * 128 + c * 4 + 0], __float_as_int(m.x));
    atomicMax((int*)&pmax[g * 128 + c * 4 + 1], __float_as_int(m.y));
    atomicMax((int*)&pmax[g * 128 + c * 4 + 2], __float_as_int(m.z));
    atomicMax((int*)&pmax[g * 128 + c * 4 + 3], __float_as_int(m.w));
    if (c == 0) atomicAdd(&pcnt[g], (float)cnt);
}

__global__ void k_final(const float* __restrict__ psum, const float* __restrict__ pmax,
                        const float* __restrict__ pcnt, const float* __restrict__ Wp,
                        const float* __restrict__ bp, float* __restrict__ out) {
    int t = blockIdx.x * blockDim.x + threadIdx.x;
    if (t >= N_GRAPHS * 256) return;
    int g = t >> 8, j = t & 255;
    float inv = 1.0f / fmaxf(pcnt[g], 1.0f);
    float acc = bp[j];
#pragma unroll 4
    for (int k = 0; k < 128; k++) acc += (psum[g * 128 + k] * inv) * Wp[k * 256 + j];
#pragma unroll 4
    for (int k = 0; k < 128; k++) acc += pmax[g * 128 + k] * Wp[(128 + k) * 256 + j];
    out[t] = fmaxf(acc, 0.f);
}

extern "C" void kernel_launch(void* const* d_in, const int* in_sizes, int n_in,
                              void* d_out, int out_size, void* d_ws, size_t ws_size,
                              hipStream_t stream) {
    const int N = N_NODES, E = N_EDGES;
    const float* x    = (const float*)d_in[0];
    const int*   ei   = (const int*)d_in[1];
    const int*   src  = ei;
    const int*   dst  = ei + E;
    const int*   batch= (const int*)d_in[2];
    const float* W_in = (const float*)d_in[3];
    const float* b_in = (const float*)d_in[4];
    const float* W1   = (const float*)d_in[5];
    const float* b1   = (const float*)d_in[6];
    const float* W2   = (const float*)d_in[7];
    const float* b2   = (const float*)d_in[8];
    const float* Wp   = (const float*)d_in[9];
    const float* bp   = (const float*)d_in[10];
    float* out = (float*)d_out;

    char* p = (char*)d_ws;
    int* counts  = (int*)p;      p += CMAT * 4;
    int* cbase   = (int*)p;      p += CMAT * 4;
    int* bsum    = (int*)p;      p += 256 * 4;
    int* bscan   = (int*)p;      p += 256 * 4;
    int* row_ptr = (int*)p;      p += (N_PAD + 64) * 4;
    int* col     = (int*)p;      p += (size_t)N_EDGES * 4;
    float* dinv  = (float*)p;    p += N_PAD * 4;
    _Float16* Wt1 = (_Float16*)p; p += 128 * 64 * 2;
    _Float16* Wt2 = (_Float16*)p; p += 128 * 128 * 2;
    float* A     = (float*)p;    p += (size_t)N_PAD * 128 * 4;  // fp16 g OR fp32 h2
    float* B     = (float*)p;    p += (size_t)N_PAD * 128 * 4;  // fp16 s OR esort
    float* psum  = (float*)p;    p += N_GRAPHS * 128 * 4;
    float* pmax  = (float*)p;    p += N_GRAPHS * 128 * 4;
    float* pcnt  = (float*)p;
    __half* Ah = (__half*)A;
    _Float16* Sh = (_Float16*)B;
    unsigned long long* esort = (unsigned long long*)B;  // alias: dead before first Sh write

    const int TB = 256;
    dim3 blk(TB);
    int gN16 = (N * 16 + TB - 1) / TB;
    int gGemm = (N + 63) / 64;

    // weight prep (independent)
    k_prep_w<<<(128 * 64 + TB - 1) / TB, blk, 0, stream>>>(W1, Wt1, 64);
    k_prep_w<<<(128 * 128 + TB - 1) / TB, blk, 0, stream>>>(W2, Wt2, 128);

    // CSR build: two-level counting sort, zero global atomics
    k_coarse_hist<<<CB, blk, 0, stream>>>(dst, counts);
    k_block_sum<<<SCAN_NB, blk, 0, stream>>>(counts, bsum, CMAT);
    k_bsum_scan<<<1, blk, 0, stream>>>(bsum, bscan, SCAN_NB);
    k_scan_write<<<SCAN_NB, blk, 0, stream>>>(counts, bscan, cbase, CMAT);
    k_coarse_scatter<<<CB, blk, 0, stream>>>(src, dst, cbase, esort);
    k_fine_fill<<<NBUCKET, blk, 0, stream>>>(esort, cbase, col, row_ptr, dinv);

    // g0 = fp16(dinv * (x@W_in + b_in))   [N,64] in Ah
    k_proj_scale<<<gN16, blk, 0, stream>>>(x, W_in, b_in, dinv, Ah, N);

    // layer 1: s0 = gather(g0) fp16 in Sh ; g1 = fp16(dinv*relu(dinv*(s0@W1)+b1)) in Ah
    k_gather_h<64><<<(N * 8 + TB - 1) / TB, blk, 0, stream>>>((const H8*)Ah, row_ptr, col, Sh, N);
    k_lin_mfma<64, true><<<gGemm, blk, 0, stream>>>(Sh, Wt1, b1, dinv, Ah, N);

    // layer 2: s1 = gather(g1) fp16 in Sh ; h2 = relu(dinv*(s1@W2)+b2) fp32 in A
    k_gather_h<128><<<(N * 16 + TB - 1) / TB, blk, 0, stream>>>((const H8*)Ah, row_ptr, col, Sh, N);
    k_lin_mfma<128, false><<<gGemm, blk, 0, stream>>>(Sh, Wt2, b2, dinv, A, N);

    // pooling
    k_pool_init<<<(N_GRAPHS * 128 + TB - 1) / TB, blk, 0, stream>>>(psum, pmax, pcnt);
    int chunks = (N + 63) / 64;
    k_pool<<<(chunks * 32 + TB - 1) / TB, blk, 0, stream>>>(A, batch, psum, pmax, pcnt, N);

    // final MLP
    k_final<<<(N_GRAPHS * 256 + TB - 1) / TB, blk, 0, stream>>>(psum, pmax, pcnt, Wp, bp, out);
}

// Round 9
// 238.917 us; speedup vs baseline: 4.9334x; 1.0214x over previous
//
#include <hip/hip_runtime.h>
#include <hip/hip_fp16.h>

#define N_NODES 50000
#define N_EDGES 800000
#define N_GRAPHS 64
#define N_PAD 50048

#define CB 256                              // coarse-pass blocks
#define EPB (N_EDGES / CB)                  // 3125 edges per block (exact)
#define NBUCKET ((N_NODES + 255) / 256)     // 196 coarse buckets (dst>>8)

typedef _Float16 f16x8 __attribute__((ext_vector_type(8)));
typedef float f32x4 __attribute__((ext_vector_type(4)));

// ---------------- prep: weight transpose->fp16, pool zero, cursor zero ----------------

__global__ void k_prep(const float* __restrict__ W1, const float* __restrict__ W2,
                       _Float16* __restrict__ Wt1, _Float16* __restrict__ Wt2,
                       float* psum, float* pmax, float* pcnt, int* totals) {
    int idx = blockIdx.x * blockDim.x + threadIdx.x;
    if (idx < 128 * 64) {                    // Wt1[n*64+k] = W1[k*128+n]
        int n = idx >> 6, k = idx & 63;
        Wt1[idx] = (_Float16)W1[k * 128 + n];
    } else if (idx < 128 * 64 + 128 * 128) { // Wt2[n*128+k] = W2[k*128+n]
        int j = idx - 128 * 64;
        int n = j >> 7, k = j & 127;
        Wt2[j] = (_Float16)W2[k * 128 + n];
    }
    if (idx < N_GRAPHS * 128) { psum[idx] = 0.f; pmax[idx] = 0.f; }
    if (idx < N_GRAPHS) pcnt[idx] = 0.f;
    if (idx < 256) totals[idx] = 0;
}

// ---------------- CSR build ----------------

// per-block LDS hist -> global bucket totals
__global__ __launch_bounds__(256) void k_coarse_hist(const int* __restrict__ dst,
                                                     int* __restrict__ totals) {
    __shared__ int hist[NBUCKET];
    int t = threadIdx.x, b = blockIdx.x;
    for (int i = t; i < NBUCKET; i += 256) hist[i] = 0;
    __syncthreads();
    int e0 = b * EPB;
    for (int e = e0 + t; e < e0 + EPB; e += 256)
        atomicAdd(&hist[dst[e] >> 8], 1);
    __syncthreads();
    for (int i = t; i < NBUCKET; i += 256)
        if (hist[i] > 0) atomicAdd(&totals[i], hist[i]);
}

// one block: exclusive scan of 196 bucket totals -> bucket_base, gcursor
__global__ void k_bucket_scan(const int* __restrict__ totals, int* __restrict__ bucket_base,
                              int* __restrict__ gcursor) {
    __shared__ int sh[256];
    int t = threadIdx.x;
    int v = (t < NBUCKET) ? totals[t] : 0;
    sh[t] = v;
    __syncthreads();
    for (int off = 1; off < 256; off <<= 1) {
        int u = (t >= off) ? sh[t - off] : 0;
        __syncthreads();
        sh[t] += u;
        __syncthreads();
    }
    if (t < NBUCKET) {
        int base = sh[t] - v;
        bucket_base[t] = base;
        gcursor[t] = base;
    }
    if (t == 0) bucket_base[NBUCKET] = N_EDGES;
}

// LDS hist -> atomic range reservation -> scatter packed (dst,src)
__global__ __launch_bounds__(256) void k_coarse_scatter(
        const int* __restrict__ src, const int* __restrict__ dst,
        int* __restrict__ gcursor, unsigned long long* __restrict__ esort) {
    __shared__ int cur[NBUCKET];
    int t = threadIdx.x, b = blockIdx.x;
    for (int i = t; i < NBUCKET; i += 256) cur[i] = 0;
    __syncthreads();
    int e0 = b * EPB;
    for (int e = e0 + t; e < e0 + EPB; e += 256)
        atomicAdd(&cur[dst[e] >> 8], 1);
    __syncthreads();
    for (int i = t; i < NBUCKET; i += 256) {
        int cnt = cur[i];
        cur[i] = (cnt > 0) ? atomicAdd(&gcursor[i], cnt) : 0;  // reserve range
    }
    __syncthreads();
    for (int e = e0 + t; e < e0 + EPB; e += 256) {
        int d = dst[e];
        int slot = atomicAdd(&cur[d >> 8], 1);
        esort[slot] = ((unsigned long long)(unsigned)d << 32) | (unsigned)src[e];
    }
}

// one block per bucket: fine hist -> row_ptr/dinv, cursor fill of col; then fused proj:
// g0[node] = fp16(dinv * (x@W_in + b_in))
__global__ __launch_bounds__(256) void k_fine_fill_proj(
        const unsigned long long* __restrict__ esort, const int* __restrict__ bucket_base,
        int* __restrict__ col, int* __restrict__ row_ptr, float* __restrict__ dinv,
        const float* __restrict__ x, const float* __restrict__ W_in,
        const float* __restrict__ b_in, _Float16* __restrict__ g0) {
    __shared__ int hist[256];
    __shared__ int sc[256];
    __shared__ int cur[256];
    int t = threadIdx.x, b = blockIdx.x;
    hist[t] = 0;
    __syncthreads();
    int base = bucket_base[b], end = bucket_base[b + 1];
    for (int e = base + t; e < end; e += 256)
        atomicAdd(&hist[(int)(esort[e] >> 32) & 255], 1);
    __syncthreads();
    int v = hist[t];
    sc[t] = v;
    __syncthreads();
    for (int off = 1; off < 256; off <<= 1) {
        int u = (t >= off) ? sc[t - off] : 0;
        __syncthreads();
        sc[t] += u;
        __syncthreads();
    }
    int start = base + sc[t] - v;
    cur[t] = start;
    int node = b * 256 + t;
    float di = rsqrtf((float)(v + 1));  // +1 self-loop
    if (node < N_NODES) {
        row_ptr[node] = start;
        dinv[node] = di;
    }
    if (b == 0 && t == 0) row_ptr[N_NODES] = N_EDGES;
    __syncthreads();
    for (int e = base + t; e < end; e += 256) {
        unsigned long long pk = esort[e];
        int slot = atomicAdd(&cur[(int)(pk >> 32) & 255], 1);
        col[slot] = (int)(pk & 0xffffffffu);
    }
    // fused input projection for this block's node
    if (node < N_NODES) {
        float xr[6];
#pragma unroll
        for (int k = 0; k < 6; k++) xr[k] = x[node * 6 + k];
#pragma unroll
        for (int oc = 0; oc < 8; oc++) {  // 8 octets of 8 cols
            f16x8 o;
#pragma unroll
            for (int j = 0; j < 8; j++) {
                int cl = oc * 8 + j;
                float acc = b_in[cl];
#pragma unroll
                for (int k = 0; k < 6; k++) acc += xr[k] * W_in[k * 64 + cl];
                o[j] = (_Float16)(acc * di);
            }
            *(f16x8*)&g0[(size_t)node * 64 + oc * 8] = o;
        }
    }
}

// ---------------- sparse gather ----------------

struct H8 { __half2 a, b, c, d; };

template <int C>
__global__ void k_gather_h(const H8* __restrict__ g, const int* __restrict__ row_ptr,
                           const int* __restrict__ col, _Float16* __restrict__ s_out, int n) {
    constexpr int CO = C / 8;
    int t = blockIdx.x * blockDim.x + threadIdx.x;
    if (t >= n * CO) return;
    int i = t / CO;
    int c = t & (CO - 1);
    float acc[8] = {};
    auto addv = [&](H8 v) {
        float2 f;
        f = __half22float2(v.a); acc[0] += f.x; acc[1] += f.y;
        f = __half22float2(v.b); acc[2] += f.x; acc[3] += f.y;
        f = __half22float2(v.c); acc[4] += f.x; acc[5] += f.y;
        f = __half22float2(v.d); acc[6] += f.x; acc[7] += f.y;
    };
    addv(g[(size_t)i * CO + c]);
    int e = row_ptr[i], e1 = row_ptr[i + 1];
    for (; e + 1 < e1; e += 2) {
        H8 v0 = g[(size_t)col[e] * CO + c];
        H8 v1 = g[(size_t)col[e + 1] * CO + c];
        addv(v0);
        addv(v1);
    }
    if (e < e1) addv(g[(size_t)col[e] * CO + c]);
    f16x8 o;
#pragma unroll
    for (int j = 0; j < 8; j++) o[j] = (_Float16)acc[j];
    *(f16x8*)&s_out[(size_t)i * C + c * 8] = o;
}

// ---------------- MFMA GEMM ----------------

template <int K, bool HALF_OUT>
__global__ __launch_bounds__(256) void k_lin_mfma(
        const _Float16* __restrict__ s_h, const _Float16* __restrict__ Wt_h,
        const float* __restrict__ b, const float* __restrict__ dinv,
        void* __restrict__ outp, int n) {
    constexpr int KP = K + 8;
    __shared__ __align__(16) _Float16 Wl[128 * KP];
    int t = threadIdx.x;
    constexpr int CH = 128 * K / 8;  // 16B chunks
    for (int c = t; c < CH; c += 256) {
        int row = c / (K / 8), off = c - row * (K / 8);
        *(f16x8*)&Wl[row * KP + off * 8] = *(const f16x8*)&Wt_h[row * K + off * 8];
    }
    __syncthreads();

    int wave = t >> 6;
    int lane = t & 63;
    int m = lane & 15;
    int quad = lane >> 4;
    int wrow0 = blockIdx.x * 64 + wave * 16;

    const _Float16* ap = s_h + (size_t)wrow0 * K + (size_t)m * K + quad * 8;

    f32x4 acc[8] = {};
#pragma unroll
    for (int k0 = 0; k0 < K; k0 += 32) {
        f16x8 a = *(const f16x8*)(ap + k0);
#pragma unroll
        for (int nt = 0; nt < 8; nt++) {
            f16x8 bw = *(const f16x8*)&Wl[(nt * 16 + m) * KP + k0 + quad * 8];
            acc[nt] = __builtin_amdgcn_mfma_f32_16x16x32_f16(a, bw, acc[nt], 0, 0, 0);
        }
    }

#pragma unroll
    for (int r = 0; r < 4; r++) {
        int row = wrow0 + quad * 4 + r;
        if (row < n) {
            float di = dinv[row];
#pragma unroll
            for (int nt = 0; nt < 8; nt++) {
                int colb = nt * 16 + m;
                float v = fmaxf(di * acc[nt][r] + b[colb], 0.f);
                if (HALF_OUT)
                    ((_Float16*)outp)[(size_t)row * 128 + colb] = (_Float16)(v * di);
                else
                    ((float*)outp)[(size_t)row * 128 + colb] = v;
            }
        }
    }
}

// ---------------- pooling + final ----------------

__global__ void k_pool(const float* __restrict__ h, const int* __restrict__ batch,
                       float* psum, float* pmax, float* pcnt, int n) {
    const int CH = 64;
    int t = blockIdx.x * blockDim.x + threadIdx.x;
    int c = t & 31;
    int chunk = t >> 5;
    int i0 = chunk * CH;
    if (i0 >= n) return;
    int i1 = min(i0 + CH, n);
    const float4* h4 = (const float4*)h;
    float4 s = {0, 0, 0, 0}, m = {0, 0, 0, 0};
    int cnt = 0;
    int g = batch[i0];
    for (int i = i0; i < i1; i++) {
        int gi = batch[i];
        if (gi != g) {
            atomicAdd(&psum[g * 128 + c * 4 + 0], s.x);
            atomicAdd(&psum[g * 128 + c * 4 + 1], s.y);
            atomicAdd(&psum[g * 128 + c * 4 + 2], s.z);
            atomicAdd(&psum[g * 128 + c * 4 + 3], s.w);
            atomicMax((int*)&pmax[g * 128 + c * 4 + 0], __float_as_int(m.x));
            atomicMax((int*)&pmax[g * 128 + c * 4 + 1], __float_as_int(m.y));
            atomicMax((int*)&pmax[g * 128 + c * 4 + 2], __float_as_int(m.z));
            atomicMax((int*)&pmax[g * 128 + c * 4 + 3], __float_as_int(m.w));
            if (c == 0) atomicAdd(&pcnt[g], (float)cnt);
            s = {0, 0, 0, 0}; m = {0, 0, 0, 0}; cnt = 0; g = gi;
        }
        float4 v = h4[(size_t)i * 32 + c];
        s.x += v.x; s.y += v.y; s.z += v.z; s.w += v.w;
        m.x = fmaxf(m.x, v.x); m.y = fmaxf(m.y, v.y);
        m.z = fmaxf(m.z, v.z); m.w = fmaxf(m.w, v.w);
        cnt++;
    }
    atomicAdd(&psum[g * 128 + c * 4 + 0], s.x);
    atomicAdd(&psum[g * 128 + c * 4 + 1], s.y);
    atomicAdd(&psum[g * 128 + c * 4 + 2], s.z);
    atomicAdd(&psum[g * 128 + c * 4 + 3], s.w);
    atomicMax((int*)&pmax[g * 128 + c * 4 + 0], __float_as_int(m.x));
    atomicMax((int*)&pmax[g * 128 + c * 4 + 1], __float_as_int(m.y));
    atomicMax((int*)&pmax[g * 128 + c * 4 + 2], __float_as_int(m.z));
    atomicMax((int*)&pmax[g * 128 + c * 4 + 3], __float_as_int(m.w));
    if (c == 0) atomicAdd(&pcnt[g], (float)cnt);
}

__global__ void k_final(const float* __restrict__ psum, const float* __restrict__ pmax,
                        const float* __restrict__ pcnt, const float* __restrict__ Wp,
                        const float* __restrict__ bp, float* __restrict__ out) {
    int t = blockIdx.x * blockDim.x + threadIdx.x;
    if (t >= N_GRAPHS * 256) return;
    int g = t >> 8, j = t & 255;
    float inv = 1.0f / fmaxf(pcnt[g], 1.0f);
    float acc = bp[j];
#pragma unroll 4
    for (int k = 0; k < 128; k++) acc += (psum[g * 128 + k] * inv) * Wp[k * 256 + j];
#pragma unroll 4
    for (int k = 0; k < 128; k++) acc += pmax[g * 128 + k] * Wp[(128 + k) * 256 + j];
    out[t] = fmaxf(acc, 0.f);
}

extern "C" void kernel_launch(void* const* d_in, const int* in_sizes, int n_in,
                              void* d_out, int out_size, void* d_ws, size_t ws_size,
                              hipStream_t stream) {
    const int N = N_NODES, E = N_EDGES;
    const float* x    = (const float*)d_in[0];
    const int*   ei   = (const int*)d_in[1];
    const int*   src  = ei;
    const int*   dst  = ei + E;
    const int*   batch= (const int*)d_in[2];
    const float* W_in = (const float*)d_in[3];
    const float* b_in = (const float*)d_in[4];
    const float* W1   = (const float*)d_in[5];
    const float* b1   = (const float*)d_in[6];
    const float* W2   = (const float*)d_in[7];
    const float* b2   = (const float*)d_in[8];
    const float* Wp   = (const float*)d_in[9];
    const float* bp   = (const float*)d_in[10];
    float* out = (float*)d_out;

    char* p = (char*)d_ws;
    int* totals      = (int*)p;   p += 256 * 4;
    int* bucket_base = (int*)p;   p += 256 * 4;
    int* gcursor     = (int*)p;   p += 256 * 4;
    int* row_ptr     = (int*)p;   p += (N_PAD + 64) * 4;
    int* col         = (int*)p;   p += (size_t)N_EDGES * 4;
    float* dinv      = (float*)p; p += N_PAD * 4;
    _Float16* Wt1    = (_Float16*)p; p += 128 * 64 * 2;
    _Float16* Wt2    = (_Float16*)p; p += 128 * 128 * 2;
    float* A         = (float*)p; p += (size_t)N_PAD * 128 * 4;  // fp16 g OR fp32 h2
    float* B         = (float*)p; p += (size_t)N_PAD * 128 * 4;  // fp16 s OR esort
    float* psum      = (float*)p; p += N_GRAPHS * 128 * 4;
    float* pmax      = (float*)p; p += N_GRAPHS * 128 * 4;
    float* pcnt      = (float*)p;
    __half* Ah = (__half*)A;
    _Float16* Gh = (_Float16*)A;
    _Float16* Sh = (_Float16*)B;
    unsigned long long* esort = (unsigned long long*)B;  // alias: dead before first Sh write

    const int TB = 256;
    dim3 blk(TB);
    int gGemm = (N + 63) / 64;

    // prep: weight transpose + pool/cursor zero
    k_prep<<<(128 * 64 + 128 * 128 + TB - 1) / TB, blk, 0, stream>>>(
        W1, W2, Wt1, Wt2, psum, pmax, pcnt, totals);

    // CSR build: hist -> tiny scan -> reservation scatter -> fine fill (+ fused proj)
    k_coarse_hist<<<CB, blk, 0, stream>>>(dst, totals);
    k_bucket_scan<<<1, blk, 0, stream>>>(totals, bucket_base, gcursor);
    k_coarse_scatter<<<CB, blk, 0, stream>>>(src, dst, gcursor, esort);
    k_fine_fill_proj<<<NBUCKET, blk, 0, stream>>>(esort, bucket_base, col, row_ptr, dinv,
                                                  x, W_in, b_in, Gh);

    // layer 1: s0 = gather(g0) fp16 in Sh ; g1 = fp16(dinv*relu(dinv*(s0@W1)+b1)) in Gh
    k_gather_h<64><<<(N * 8 + TB - 1) / TB, blk, 0, stream>>>((const H8*)Gh, row_ptr, col, Sh, N);
    k_lin_mfma<64, true><<<gGemm, blk, 0, stream>>>(Sh, Wt1, b1, dinv, Gh, N);

    // layer 2: s1 = gather(g1) fp16 in Sh ; h2 = relu(dinv*(s1@W2)+b2) fp32 in A
    k_gather_h<128><<<(N * 16 + TB - 1) / TB, blk, 0, stream>>>((const H8*)Gh, row_ptr, col, Sh, N);
    k_lin_mfma<128, false><<<gGemm, blk, 0, stream>>>(Sh, Wt2, b2, dinv, A, N);

    // pooling
    int chunks = (N + 63) / 64;
    k_pool<<<(chunks * 32 + TB - 1) / TB, blk, 0, stream>>>(A, batch, psum, pmax, pcnt, N);

    // final MLP
    k_final<<<(N_GRAPHS * 256 + TB - 1) / TB, blk, 0, stream>>>(psum, pmax, pcnt, Wp, bp, out);
}

// Round 10
// 237.418 us; speedup vs baseline: 4.9646x; 1.0063x over previous
//
#include <hip/hip_runtime.h>
#include <hip/hip_fp16.h>

#define N_NODES 50000
#define N_EDGES 800000
#define N_GRAPHS 64
#define N_PAD 50048

#define CB 256                              // coarse-pass blocks
#define EPB (N_EDGES / CB)                  // 3125 edges per block (exact)
#define NBUCKET ((N_NODES + 255) / 256)     // 196 coarse buckets (dst>>8)

typedef _Float16 f16x8 __attribute__((ext_vector_type(8)));
typedef float f32x4 __attribute__((ext_vector_type(4)));

struct H8 { __half2 a, b, c, d; };

// ---------------- prep: weight transpose->fp16, pool zero, cursor zero ----------------

__global__ void k_prep(const float* __restrict__ W1, const float* __restrict__ W2,
                       _Float16* __restrict__ Wt1, _Float16* __restrict__ Wt2,
                       float* psum, float* pmax, float* pcnt, int* totals) {
    int idx = blockIdx.x * blockDim.x + threadIdx.x;
    if (idx < 128 * 64) {                    // Wt1[n*64+k] = W1[k*128+n]
        int n = idx >> 6, k = idx & 63;
        Wt1[idx] = (_Float16)W1[k * 128 + n];
    } else if (idx < 128 * 64 + 128 * 128) { // Wt2[n*128+k] = W2[k*128+n]
        int j = idx - 128 * 64;
        int n = j >> 7, k = j & 127;
        Wt2[j] = (_Float16)W2[k * 128 + n];
    }
    if (idx < N_GRAPHS * 128) { psum[idx] = 0.f; pmax[idx] = 0.f; }
    if (idx < N_GRAPHS) pcnt[idx] = 0.f;
    if (idx < 256) totals[idx] = 0;
}

// ---------------- CSR build ----------------

__global__ __launch_bounds__(256) void k_coarse_hist(const int* __restrict__ dst,
                                                     int* __restrict__ totals) {
    __shared__ int hist[NBUCKET];
    int t = threadIdx.x, b = blockIdx.x;
    for (int i = t; i < NBUCKET; i += 256) hist[i] = 0;
    __syncthreads();
    int e0 = b * EPB;
    for (int e = e0 + t; e < e0 + EPB; e += 256)
        atomicAdd(&hist[dst[e] >> 8], 1);
    __syncthreads();
    for (int i = t; i < NBUCKET; i += 256)
        if (hist[i] > 0) atomicAdd(&totals[i], hist[i]);
}

__global__ void k_bucket_scan(const int* __restrict__ totals, int* __restrict__ bucket_base,
                              int* __restrict__ gcursor) {
    __shared__ int sh[256];
    int t = threadIdx.x;
    int v = (t < NBUCKET) ? totals[t] : 0;
    sh[t] = v;
    __syncthreads();
    for (int off = 1; off < 256; off <<= 1) {
        int u = (t >= off) ? sh[t - off] : 0;
        __syncthreads();
        sh[t] += u;
        __syncthreads();
    }
    if (t < NBUCKET) {
        int base = sh[t] - v;
        bucket_base[t] = base;
        gcursor[t] = base;
    }
    if (t == 0) bucket_base[NBUCKET] = N_EDGES;
}

// LDS hist -> atomic range reservation -> scatter packed ((dst&255)<<16 | src)
__global__ __launch_bounds__(256) void k_coarse_scatter(
        const int* __restrict__ src, const int* __restrict__ dst,
        int* __restrict__ gcursor, unsigned int* __restrict__ esort) {
    __shared__ int cur[NBUCKET];
    int t = threadIdx.x, b = blockIdx.x;
    for (int i = t; i < NBUCKET; i += 256) cur[i] = 0;
    __syncthreads();
    int e0 = b * EPB;
    for (int e = e0 + t; e < e0 + EPB; e += 256)
        atomicAdd(&cur[dst[e] >> 8], 1);
    __syncthreads();
    for (int i = t; i < NBUCKET; i += 256) {
        int cnt = cur[i];
        cur[i] = (cnt > 0) ? atomicAdd(&gcursor[i], cnt) : 0;  // reserve range
    }
    __syncthreads();
    for (int e = e0 + t; e < e0 + EPB; e += 256) {
        int d = dst[e];
        int slot = atomicAdd(&cur[d >> 8], 1);
        esort[slot] = ((unsigned)(d & 255) << 16) | (unsigned)src[e];  // src < 2^16
    }
}

// one block per bucket: fine hist -> row_ptr/dinv, cursor fill of col; fused input proj
__global__ __launch_bounds__(256) void k_fine_fill_proj(
        const unsigned int* __restrict__ esort, const int* __restrict__ bucket_base,
        int* __restrict__ col, int* __restrict__ row_ptr, float* __restrict__ dinv,
        const float* __restrict__ x, const float* __restrict__ W_in,
        const float* __restrict__ b_in, _Float16* __restrict__ g0) {
    __shared__ int hist[256];
    __shared__ int sc[256];
    __shared__ int cur[256];
    int t = threadIdx.x, b = blockIdx.x;
    hist[t] = 0;
    __syncthreads();
    int base = bucket_base[b], end = bucket_base[b + 1];
    for (int e = base + t; e < end; e += 256)
        atomicAdd(&hist[(esort[e] >> 16) & 255], 1);
    __syncthreads();
    int v = hist[t];
    sc[t] = v;
    __syncthreads();
    for (int off = 1; off < 256; off <<= 1) {
        int u = (t >= off) ? sc[t - off] : 0;
        __syncthreads();
        sc[t] += u;
        __syncthreads();
    }
    int start = base + sc[t] - v;
    cur[t] = start;
    int node = b * 256 + t;
    float di = rsqrtf((float)(v + 1));  // +1 self-loop
    if (node < N_NODES) {
        row_ptr[node] = start;
        dinv[node] = di;
    }
    if (b == 0 && t == 0) row_ptr[N_NODES] = N_EDGES;
    __syncthreads();
    for (int e = base + t; e < end; e += 256) {
        unsigned pk = esort[e];
        int slot = atomicAdd(&cur[(pk >> 16) & 255], 1);
        col[slot] = (int)(pk & 0xffffu);
    }
    // fused input projection for this block's node
    if (node < N_NODES) {
        float xr[6];
#pragma unroll
        for (int k = 0; k < 6; k++) xr[k] = x[node * 6 + k];
#pragma unroll
        for (int oc = 0; oc < 8; oc++) {  // 8 octets of 8 cols
            f16x8 o;
#pragma unroll
            for (int j = 0; j < 8; j++) {
                int cl = oc * 8 + j;
                float acc = b_in[cl];
#pragma unroll
                for (int k = 0; k < 6; k++) acc += xr[k] * W_in[k * 64 + cl];
                o[j] = (_Float16)(acc * di);
            }
            *(f16x8*)&g0[(size_t)node * 64 + oc * 8] = o;
        }
    }
}

// ---------------- fused gather + MFMA GEMM ----------------
// Block = 256 threads = 4 waves, 64 rows. Phase 1: gather block rows into LDS
// Sl[64][K+8] fp16 (fp32 acc). Phase 2: MFMA from Sl x LDS-staged Wt.
template <int K, bool HALF_OUT>
__global__ __launch_bounds__(256) void k_gnn(
        const _Float16* __restrict__ g, const int* __restrict__ row_ptr,
        const int* __restrict__ col, const _Float16* __restrict__ Wt_h,
        const float* __restrict__ b, const float* __restrict__ dinv,
        void* __restrict__ outp, int n) {
    constexpr int KP = K + 8;
    constexpr int CO8 = K / 8;    // H8 chunks per row
    constexpr int CW = K / 4;     // channels per gather task
    constexpr int CWO = CW / 8;   // H8 per task (4 for K=128, 2 for K=64)
    __shared__ __align__(16) _Float16 Wl[128 * KP];
    __shared__ __align__(16) _Float16 Sl[64 * KP];
    int t = threadIdx.x;

    // stage W
    constexpr int CH = 128 * CO8;
    for (int c = t; c < CH; c += 256) {
        int row = c / CO8, off = c - row * CO8;
        *(f16x8*)&Wl[row * KP + off * 8] = *(const f16x8*)&Wt_h[row * K + off * 8];
    }

    // gather phase: thread t handles (row_local = t>>2, chunk ck = t&3)
    {
        int row_local = t >> 2, ck = t & 3;
        int row = blockIdx.x * 64 + row_local;
        float acc[CW] = {};
        const H8* gb = (const H8*)g;
        if (row < n) {
            size_t rb = (size_t)row * CO8 + ck * CWO;
            auto addv = [&](H8 v, int j8) {
                float2 f;
                f = __half22float2(v.a); acc[j8 + 0] += f.x; acc[j8 + 1] += f.y;
                f = __half22float2(v.b); acc[j8 + 2] += f.x; acc[j8 + 3] += f.y;
                f = __half22float2(v.c); acc[j8 + 4] += f.x; acc[j8 + 5] += f.y;
                f = __half22float2(v.d); acc[j8 + 6] += f.x; acc[j8 + 7] += f.y;
            };
#pragma unroll
            for (int j = 0; j < CWO; j++) addv(gb[rb + j], j * 8);  // self
            int e = row_ptr[row], e1 = row_ptr[row + 1];
            for (; e + 1 < e1; e += 2) {
                size_t b0 = (size_t)col[e] * CO8 + ck * CWO;
                size_t b1 = (size_t)col[e + 1] * CO8 + ck * CWO;
                H8 v0[CWO], v1[CWO];
#pragma unroll
                for (int j = 0; j < CWO; j++) { v0[j] = gb[b0 + j]; v1[j] = gb[b1 + j]; }
#pragma unroll
                for (int j = 0; j < CWO; j++) { addv(v0[j], j * 8); addv(v1[j], j * 8); }
            }
            if (e < e1) {
                size_t b0 = (size_t)col[e] * CO8 + ck * CWO;
#pragma unroll
                for (int j = 0; j < CWO; j++) addv(gb[b0 + j], j * 8);
            }
        }
#pragma unroll
        for (int j = 0; j < CWO; j++) {
            f16x8 o;
#pragma unroll
            for (int q = 0; q < 8; q++) o[q] = (_Float16)acc[j * 8 + q];
            *(f16x8*)&Sl[row_local * KP + ck * CW + j * 8] = o;
        }
    }
    __syncthreads();

    // MFMA phase
    int wave = t >> 6;
    int lane = t & 63;
    int m = lane & 15;
    int quad = lane >> 4;
    int wrow0 = blockIdx.x * 64 + wave * 16;

    f32x4 acc[8] = {};
#pragma unroll
    for (int k0 = 0; k0 < K; k0 += 32) {
        f16x8 a = *(const f16x8*)&Sl[(wave * 16 + m) * KP + k0 + quad * 8];
#pragma unroll
        for (int nt = 0; nt < 8; nt++) {
            f16x8 bw = *(const f16x8*)&Wl[(nt * 16 + m) * KP + k0 + quad * 8];
            acc[nt] = __builtin_amdgcn_mfma_f32_16x16x32_f16(a, bw, acc[nt], 0, 0, 0);
        }
    }

#pragma unroll
    for (int r = 0; r < 4; r++) {
        int row = wrow0 + quad * 4 + r;
        if (row < n) {
            float di = dinv[row];
#pragma unroll
            for (int nt = 0; nt < 8; nt++) {
                int colb = nt * 16 + m;
                float v = fmaxf(di * acc[nt][r] + b[colb], 0.f);
                if (HALF_OUT)
                    ((_Float16*)outp)[(size_t)row * 128 + colb] = (_Float16)(v * di);
                else
                    ((float*)outp)[(size_t)row * 128 + colb] = v;
            }
        }
    }
}

// ---------------- pooling + final ----------------

__global__ void k_pool(const float* __restrict__ h, const int* __restrict__ batch,
                       float* psum, float* pmax, float* pcnt, int n) {
    const int CH = 64;
    int t = blockIdx.x * blockDim.x + threadIdx.x;
    int c = t & 31;
    int chunk = t >> 5;
    int i0 = chunk * CH;
    if (i0 >= n) return;
    int i1 = min(i0 + CH, n);
    const float4* h4 = (const float4*)h;
    float4 s = {0, 0, 0, 0}, m = {0, 0, 0, 0};
    int cnt = 0;
    int g = batch[i0];
    for (int i = i0; i < i1; i++) {
        int gi = batch[i];
        if (gi != g) {
            atomicAdd(&psum[g * 128 + c * 4 + 0], s.x);
            atomicAdd(&psum[g * 128 + c * 4 + 1], s.y);
            atomicAdd(&psum[g * 128 + c * 4 + 2], s.z);
            atomicAdd(&psum[g * 128 + c * 4 + 3], s.w);
            atomicMax((int*)&pmax[g * 128 + c * 4 + 0], __float_as_int(m.x));
            atomicMax((int*)&pmax[g * 128 + c * 4 + 1], __float_as_int(m.y));
            atomicMax((int*)&pmax[g * 128 + c * 4 + 2], __float_as_int(m.z));
            atomicMax((int*)&pmax[g * 128 + c * 4 + 3], __float_as_int(m.w));
            if (c == 0) atomicAdd(&pcnt[g], (float)cnt);
            s = {0, 0, 0, 0}; m = {0, 0, 0, 0}; cnt = 0; g = gi;
        }
        float4 v = h4[(size_t)i * 32 + c];
        s.x += v.x; s.y += v.y; s.z += v.z; s.w += v.w;
        m.x = fmaxf(m.x, v.x); m.y = fmaxf(m.y, v.y);
        m.z = fmaxf(m.z, v.z); m.w = fmaxf(m.w, v.w);
        cnt++;
    }
    atomicAdd(&psum[g * 128 + c * 4 + 0], s.x);
    atomicAdd(&psum[g * 128 + c * 4 + 1], s.y);
    atomicAdd(&psum[g * 128 + c * 4 + 2], s.z);
    atomicAdd(&psum[g * 128 + c * 4 + 3], s.w);
    atomicMax((int*)&pmax[g * 128 + c * 4 + 0], __float_as_int(m.x));
    atomicMax((int*)&pmax[g * 128 + c * 4 + 1], __float_as_int(m.y));
    atomicMax((int*)&pmax[g * 128 + c * 4 + 2], __float_as_int(m.z));
    atomicMax((int*)&pmax[g * 128 + c * 4 + 3], __float_as_int(m.w));
    if (c == 0) atomicAdd(&pcnt[g], (float)cnt);
}

__global__ void k_final(const float* __restrict__ psum, const float* __restrict__ pmax,
                        const float* __restrict__ pcnt, const float* __restrict__ Wp,
                        const float* __restrict__ bp, float* __restrict__ out) {
    int t = blockIdx.x * blockDim.x + threadIdx.x;
    if (t >= N_GRAPHS * 256) return;
    int g = t >> 8, j = t & 255;
    float inv = 1.0f / fmaxf(pcnt[g], 1.0f);
    float acc = bp[j];
#pragma unroll 4
    for (int k = 0; k < 128; k++) acc += (psum[g * 128 + k] * inv) * Wp[k * 256 + j];
#pragma unroll 4
    for (int k = 0; k < 128; k++) acc += pmax[g * 128 + k] * Wp[(128 + k) * 256 + j];
    out[t] = fmaxf(acc, 0.f);
}

extern "C" void kernel_launch(void* const* d_in, const int* in_sizes, int n_in,
                              void* d_out, int out_size, void* d_ws, size_t ws_size,
                              hipStream_t stream) {
    const int N = N_NODES, E = N_EDGES;
    const float* x    = (const float*)d_in[0];
    const int*   ei   = (const int*)d_in[1];
    const int*   src  = ei;
    const int*   dst  = ei + E;
    const int*   batch= (const int*)d_in[2];
    const float* W_in = (const float*)d_in[3];
    const float* b_in = (const float*)d_in[4];
    const float* W1   = (const float*)d_in[5];
    const float* b1   = (const float*)d_in[6];
    const float* W2   = (const float*)d_in[7];
    const float* b2   = (const float*)d_in[8];
    const float* Wp   = (const float*)d_in[9];
    const float* bp   = (const float*)d_in[10];
    float* out = (float*)d_out;

    char* p = (char*)d_ws;
    int* totals      = (int*)p;   p += 256 * 4;
    int* bucket_base = (int*)p;   p += 256 * 4;
    int* gcursor     = (int*)p;   p += 256 * 4;
    int* row_ptr     = (int*)p;   p += (N_PAD + 64) * 4;
    int* col         = (int*)p;   p += (size_t)N_EDGES * 4;
    unsigned* esort  = (unsigned*)p; p += (size_t)N_EDGES * 4;
    float* dinv      = (float*)p; p += N_PAD * 4;
    _Float16* Wt1    = (_Float16*)p; p += 128 * 64 * 2;
    _Float16* Wt2    = (_Float16*)p; p += 128 * 128 * 2;
    _Float16* g0h    = (_Float16*)p; p += (size_t)N_PAD * 64 * 2;
    _Float16* g1h    = (_Float16*)p; p += (size_t)N_PAD * 128 * 2;
    float* h2        = (float*)p; p += (size_t)N_PAD * 128 * 4;
    float* psum      = (float*)p; p += N_GRAPHS * 128 * 4;
    float* pmax      = (float*)p; p += N_GRAPHS * 128 * 4;
    float* pcnt      = (float*)p;

    const int TB = 256;
    dim3 blk(TB);
    int gGemm = (N + 63) / 64;

    // prep: weight transpose + pool/cursor zero
    k_prep<<<(128 * 64 + 128 * 128 + TB - 1) / TB, blk, 0, stream>>>(
        W1, W2, Wt1, Wt2, psum, pmax, pcnt, totals);

    // CSR build
    k_coarse_hist<<<CB, blk, 0, stream>>>(dst, totals);
    k_bucket_scan<<<1, blk, 0, stream>>>(totals, bucket_base, gcursor);
    k_coarse_scatter<<<CB, blk, 0, stream>>>(src, dst, gcursor, esort);
    k_fine_fill_proj<<<NBUCKET, blk, 0, stream>>>(esort, bucket_base, col, row_ptr, dinv,
                                                  x, W_in, b_in, g0h);

    // layer 1: fused gather(g0)+GEMM -> g1 = fp16(dinv*relu(dinv*(s0@W1)+b1))
    k_gnn<64, true><<<gGemm, blk, 0, stream>>>(g0h, row_ptr, col, Wt1, b1, dinv, g1h, N);

    // layer 2: fused gather(g1)+GEMM -> h2 = relu(dinv*(s1@W2)+b2) fp32
    k_gnn<128, false><<<gGemm, blk, 0, stream>>>(g1h, row_ptr, col, Wt2, b2, dinv, h2, N);

    // pooling
    int chunks = (N + 63) / 64;
    k_pool<<<(chunks * 32 + TB - 1) / TB, blk, 0, stream>>>(h2, batch, psum, pmax, pcnt, N);

    // final MLP
    k_final<<<(N_GRAPHS * 256 + TB - 1) / TB, blk, 0, stream>>>(psum, pmax, pcnt, Wp, bp, out);
}